// Round 2
// baseline (911.339 us; speedup 1.0000x reference)
//
#include <hip/hip_runtime.h>
#include <math.h>

#define NNODES 20000
#define NEDGES 400000
#define INC    768
#define HIDC   128
#define NHEADS 4
#define NEG_SLOPE 0.2f

// ============================ CSR build ============================

__global__ void k_zero(int* __restrict__ p, int n) {
  int i = blockIdx.x * blockDim.x + threadIdx.x;
  if (i < n) p[i] = 0;
}

// edges = original E edges + N self-loops
__global__ void k_count(const int* __restrict__ ei, int* __restrict__ cnt) {
  int i = blockIdx.x * blockDim.x + threadIdx.x;
  const int tot = NEDGES + NNODES;
  if (i >= tot) return;
  int dst = (i < NEDGES) ? ei[NEDGES + i] : (i - NEDGES);
  atomicAdd(&cnt[dst], 1);
}

__global__ void k_scan(const int* __restrict__ cnt, int* __restrict__ row_ptr,
                       int* __restrict__ fill) {
  __shared__ int part[1024];
  int t = threadIdx.x;
  const int chunk = (NNODES + 1023) / 1024;
  int lo = t * chunk, hi = min(lo + chunk, NNODES);
  int s = 0;
  for (int i = lo; i < hi; ++i) s += cnt[i];
  part[t] = s;
  __syncthreads();
  for (int off = 1; off < 1024; off <<= 1) {
    int v = (t >= off) ? part[t - off] : 0;
    __syncthreads();
    part[t] += v;
    __syncthreads();
  }
  int pref = (t == 0) ? 0 : part[t - 1];
  for (int i = lo; i < hi; ++i) {
    row_ptr[i] = pref;
    fill[i] = pref;
    pref += cnt[i];
  }
  if (t == 1023) row_ptr[NNODES] = part[1023];
}

__global__ void k_fill(const int* __restrict__ ei, int* __restrict__ fill,
                       int* __restrict__ col) {
  int i = blockIdx.x * blockDim.x + threadIdx.x;
  const int tot = NEDGES + NNODES;
  if (i >= tot) return;
  int srcv, dstv;
  if (i < NEDGES) { srcv = ei[i]; dstv = ei[NEDGES + i]; }
  else            { srcv = i - NEDGES; dstv = srcv; }
  int pos = atomicAdd(&fill[dstv], 1);
  col[pos] = srcv;
}

// ============================ fp32 GEMM ============================
// C[M,N] = A[M,K] @ B[K,N], all row-major. BM=BN=64, BK=16, 256 thr, 4x4/thr.
__global__ __launch_bounds__(256) void k_gemm(
    const float* __restrict__ A, const float* __restrict__ B,
    float* __restrict__ C, int M, int N, int K) {
  __shared__ float As[16][64];
  __shared__ float Bs[16][64];
  int tid = threadIdx.x;
  int bm = blockIdx.y, bn = blockIdx.x;
  int tm = tid >> 4, tn = tid & 15;  // 16x16 threads
  float acc[4][4] = {{0.f}};

  int arow = bm * 64 + (tid >> 2);
  int acol = (tid & 3) * 4;
  int brow = tid >> 4;
  int bcol = bn * 64 + (tid & 15) * 4;

  for (int k0 = 0; k0 < K; k0 += 16) {
    float4 av = make_float4(0.f, 0.f, 0.f, 0.f);
    if (arow < M) av = *(const float4*)&A[(size_t)arow * K + k0 + acol];
    As[acol + 0][tid >> 2] = av.x;
    As[acol + 1][tid >> 2] = av.y;
    As[acol + 2][tid >> 2] = av.z;
    As[acol + 3][tid >> 2] = av.w;
    float4 bv = *(const float4*)&B[(size_t)(k0 + brow) * N + bcol];
    *(float4*)&Bs[brow][(tid & 15) * 4] = bv;
    __syncthreads();
#pragma unroll
    for (int kk = 0; kk < 16; ++kk) {
      float a[4], b[4];
#pragma unroll
      for (int i = 0; i < 4; ++i) a[i] = As[kk][tm * 4 + i];
#pragma unroll
      for (int j = 0; j < 4; ++j) b[j] = Bs[kk][tn * 4 + j];
#pragma unroll
      for (int i = 0; i < 4; ++i)
#pragma unroll
        for (int j = 0; j < 4; ++j) acc[i][j] += a[i] * b[j];
    }
    __syncthreads();
  }
#pragma unroll
  for (int i = 0; i < 4; ++i) {
    int row = bm * 64 + tm * 4 + i;
    if (row < M) {
#pragma unroll
      for (int j = 0; j < 4; ++j)
        C[(size_t)row * N + bn * 64 + tn * 4 + j] = acc[i][j];
    }
  }
}

// ======================= per-node alpha dots =======================
// block = H*64; wave w handles head w; lane handles channels l, l+64 (C=128)
__global__ void k_alpha(const float* __restrict__ h,
                        const float* __restrict__ a_src,
                        const float* __restrict__ a_dst,
                        float* __restrict__ asrc, float* __restrict__ adst,
                        int H) {
  const int C = HIDC;
  int n = blockIdx.x;
  int w = threadIdx.x >> 6;
  int l = threadIdx.x & 63;
  const float* hr = h + (size_t)n * H * C + w * C;
  float h0 = hr[l], h1 = hr[l + 64];
  float s1 = h0 * a_src[w * C + l] + h1 * a_src[w * C + l + 64];
  float s2 = h0 * a_dst[w * C + l] + h1 * a_dst[w * C + l + 64];
#pragma unroll
  for (int off = 32; off; off >>= 1) {
    s1 += __shfl_xor(s1, off);
    s2 += __shfl_xor(s2, off);
  }
  if (l == 0) {
    asrc[n * H + w] = s1;
    adst[n * H + w] = s2;
  }
}

// ========================= GAT aggregation =========================
// block = H*64; wave w = head w; lane handles channels l, l+64 (C=128)
__global__ void k_aggregate(const float* __restrict__ h,     // [N, H*C]
                            const float* __restrict__ asrc,  // [N, H]
                            const float* __restrict__ adst,  // [N, H]
                            const int* __restrict__ row_ptr,
                            const int* __restrict__ col,
                            const float* __restrict__ bias,  // [H*C]
                            float* __restrict__ out,         // [N, H*C]
                            int H, int applyElu) {
  const int C = HIDC;
  int n = blockIdx.x;
  int w = threadIdx.x >> 6;
  int l = threadIdx.x & 63;
  int HC = H * C;
  int r0 = row_ptr[n], r1 = row_ptr[n + 1];
  float adn = adst[n * H + w];

  // pass 1: per-head max over incoming edges
  float m = -INFINITY;
  for (int j = r0 + l; j < r1; j += 64) {
    int s = col[j];
    float e = asrc[s * H + w] + adn;
    e = e > 0.f ? e : NEG_SLOPE * e;
    m = fmaxf(m, e);
  }
#pragma unroll
  for (int off = 32; off; off >>= 1) m = fmaxf(m, __shfl_xor(m, off));

  // pass 2: exp-weighted accumulation (normalize at the end)
  float acc0 = 0.f, acc1 = 0.f, ssum = 0.f;
  for (int j = r0; j < r1; ++j) {
    int s = col[j];
    float e = asrc[s * H + w] + adn;
    e = e > 0.f ? e : NEG_SLOPE * e;
    float p = __expf(e - m);
    ssum += p;
    const float* hr = h + (size_t)s * HC + w * C;
    acc0 += p * hr[l];
    acc1 += p * hr[l + 64];
  }
  float inv = 1.f / (ssum + 1e-16f);
  float o0 = acc0 * inv + bias[w * C + l];
  float o1 = acc1 * inv + bias[w * C + l + 64];
  if (applyElu) {
    o0 = o0 > 0.f ? o0 : (__expf(o0) - 1.f);
    o1 = o1 > 0.f ? o1 : (__expf(o1) - 1.f);
  }
  out[(size_t)n * HC + w * C + l] = o0;
  out[(size_t)n * HC + w * C + l + 64] = o1;
}

// ============================ launcher ============================

extern "C" void kernel_launch(void* const* d_in, const int* in_sizes, int n_in,
                              void* d_out, int out_size, void* d_ws, size_t ws_size,
                              hipStream_t stream) {
  const float* x      = (const float*)d_in[0];
  const int*   ei     = (const int*)d_in[1];
  const float* W1     = (const float*)d_in[2];
  const float* a1_src = (const float*)d_in[3];
  const float* a1_dst = (const float*)d_in[4];
  const float* b1     = (const float*)d_in[5];
  const float* W2     = (const float*)d_in[6];
  const float* a2_src = (const float*)d_in[7];
  const float* a2_dst = (const float*)d_in[8];
  const float* b2     = (const float*)d_in[9];
  const float* W3     = (const float*)d_in[10];
  const float* a3_src = (const float*)d_in[11];
  const float* a3_dst = (const float*)d_in[12];
  const float* b3     = (const float*)d_in[13];
  float* out = (float*)d_out;

  // workspace layout
  char* ws = (char*)d_ws;
  size_t off = 0;
  auto alloc = [&](size_t bytes) {
    size_t r = off;
    off = (off + bytes + 255) & ~(size_t)255;
    return r;
  };
  float* hA      = (float*)(ws + alloc((size_t)NNODES * 512 * 4));
  float* hB      = (float*)(ws + alloc((size_t)NNODES * 512 * 4));
  float* asrc    = (float*)(ws + alloc((size_t)NNODES * NHEADS * 4));
  float* adst    = (float*)(ws + alloc((size_t)NNODES * NHEADS * 4));
  int*   row_ptr = (int*)(ws + alloc((size_t)(NNODES + 1) * 4));
  int*   fill    = (int*)(ws + alloc((size_t)NNODES * 4));
  int*   cnt     = (int*)(ws + alloc((size_t)NNODES * 4));
  int*   colv    = (int*)(ws + alloc((size_t)(NEDGES + NNODES) * 4));

  const int TOT = NEDGES + NNODES;

  // ---- build CSR (by dst) ----
  k_zero<<<(NNODES + 255) / 256, 256, 0, stream>>>(cnt, NNODES);
  k_count<<<(TOT + 255) / 256, 256, 0, stream>>>(ei, cnt);
  k_scan<<<1, 1024, 0, stream>>>(cnt, row_ptr, fill);
  k_fill<<<(TOT + 255) / 256, 256, 0, stream>>>(ei, fill, colv);

  // ---- layer 1: 768 -> 4x128, concat, ELU ----
  k_gemm<<<dim3(512 / 64, (NNODES + 63) / 64), 256, 0, stream>>>(
      x, W1, hA, NNODES, 512, INC);
  k_alpha<<<NNODES, NHEADS * 64, 0, stream>>>(hA, a1_src, a1_dst, asrc, adst, NHEADS);
  k_aggregate<<<NNODES, NHEADS * 64, 0, stream>>>(hA, asrc, adst, row_ptr, colv,
                                                  b1, hB, NHEADS, 1);

  // ---- layer 2: 512 -> 4x128, concat, ELU ----
  k_gemm<<<dim3(512 / 64, (NNODES + 63) / 64), 256, 0, stream>>>(
      hB, W2, hA, NNODES, 512, 512);
  k_alpha<<<NNODES, NHEADS * 64, 0, stream>>>(hA, a2_src, a2_dst, asrc, adst, NHEADS);
  k_aggregate<<<NNODES, NHEADS * 64, 0, stream>>>(hA, asrc, adst, row_ptr, colv,
                                                  b2, hB, NHEADS, 1);

  // ---- layer 3: 512 -> 128, 1 head, mean(=identity), no ELU ----
  k_gemm<<<dim3(128 / 64, (NNODES + 63) / 64), 256, 0, stream>>>(
      hB, W3, hA, NNODES, 128, 512);
  k_alpha<<<NNODES, 64, 0, stream>>>(hA, a3_src, a3_dst, asrc, adst, 1);
  k_aggregate<<<NNODES, 64, 0, stream>>>(hA, asrc, adst, row_ptr, colv,
                                         b3, out, 1, 0);
}

// Round 3
// 668.000 us; speedup vs baseline: 1.3643x; 1.3643x over previous
//
#include <hip/hip_runtime.h>
#include <math.h>

#define NNODES 20000
#define MPAD   20096   // NNODES rounded up to 128
#define NEDGES 400000
#define INC    768
#define HIDC   128
#define NHEADS 4
#define NEG_SLOPE 0.2f

typedef __attribute__((ext_vector_type(8))) short bf16x8;
typedef __attribute__((ext_vector_type(4))) float f32x4;

// round-to-nearest-even fp32 -> bf16 (bits)
__device__ __forceinline__ unsigned short bf16hi(float v) {
  unsigned u = __float_as_uint(v);
  return (unsigned short)((u + 0x7fffu + ((u >> 16) & 1u)) >> 16);
}

__device__ __forceinline__ void gload16(const void* g, void* l) {
  __builtin_amdgcn_global_load_lds(
      (const __attribute__((address_space(1))) unsigned int*)g,
      (__attribute__((address_space(3))) unsigned int*)l, 16, 0, 0);
}

// ============================ CSR build ============================

__global__ void k_zero(int* __restrict__ p, int n) {
  int i = blockIdx.x * blockDim.x + threadIdx.x;
  if (i < n) p[i] = 0;
}

__global__ void k_count(const int* __restrict__ ei, int* __restrict__ cnt) {
  int i = blockIdx.x * blockDim.x + threadIdx.x;
  const int tot = NEDGES + NNODES;
  if (i >= tot) return;
  int dst = (i < NEDGES) ? ei[NEDGES + i] : (i - NEDGES);
  atomicAdd(&cnt[dst], 1);
}

__global__ void k_scan(const int* __restrict__ cnt, int* __restrict__ row_ptr,
                       int* __restrict__ fill) {
  __shared__ int part[1024];
  int t = threadIdx.x;
  const int chunk = (NNODES + 1023) / 1024;
  int lo = t * chunk, hi = min(lo + chunk, NNODES);
  int s = 0;
  for (int i = lo; i < hi; ++i) s += cnt[i];
  part[t] = s;
  __syncthreads();
  for (int off = 1; off < 1024; off <<= 1) {
    int v = (t >= off) ? part[t - off] : 0;
    __syncthreads();
    part[t] += v;
    __syncthreads();
  }
  int pref = (t == 0) ? 0 : part[t - 1];
  for (int i = lo; i < hi; ++i) {
    row_ptr[i] = pref;
    fill[i] = pref;
    pref += cnt[i];
  }
  if (t == 1023) row_ptr[NNODES] = part[1023];
}

__global__ void k_fill(const int* __restrict__ ei, int* __restrict__ fill,
                       int* __restrict__ col) {
  int i = blockIdx.x * blockDim.x + threadIdx.x;
  const int tot = NEDGES + NNODES;
  if (i >= tot) return;
  int srcv, dstv;
  if (i < NEDGES) { srcv = ei[i]; dstv = ei[NEDGES + i]; }
  else            { srcv = i - NEDGES; dstv = srcv; }
  int pos = atomicAdd(&fill[dstv], 1);
  col[pos] = srcv;
}

// ========================= decompose kernels =========================

// elementwise fp32 -> (hi, lo) bf16
__global__ void k_decomp(const float* __restrict__ in, short* __restrict__ hi,
                         short* __restrict__ lo, int n) {
  int i = blockIdx.x * blockDim.x + threadIdx.x;
  if (i >= n) return;
  float v = in[i];
  unsigned short h = bf16hi(v);
  float hf = __uint_as_float((unsigned)h << 16);
  hi[i] = (short)h;
  lo[i] = (short)bf16hi(v - hf);
}

// W [K][N] fp32 -> W^T hi/lo [N][K] bf16 (LDS-tiled transpose)
__global__ __launch_bounds__(256) void k_decomp_wt(
    const float* __restrict__ W, short* __restrict__ th, short* __restrict__ tl,
    int K, int N) {
  __shared__ float t[32][33];
  int bn = blockIdx.x, bk = blockIdx.y;
  int tx = threadIdx.x & 31, ty = threadIdx.x >> 5;  // 32 x 8
#pragma unroll
  for (int r = 0; r < 4; ++r)
    t[ty + r * 8][tx] = W[(size_t)(bk * 32 + ty + r * 8) * N + bn * 32 + tx];
  __syncthreads();
#pragma unroll
  for (int r = 0; r < 4; ++r) {
    int n = bn * 32 + ty + r * 8;
    int k = bk * 32 + tx;
    float v = t[tx][ty + r * 8];
    unsigned short h = bf16hi(v);
    float hf = __uint_as_float((unsigned)h << 16);
    th[(size_t)n * K + k] = (short)h;
    tl[(size_t)n * K + k] = (short)bf16hi(v - hf);
  }
}

// ==================== split-bf16 MFMA GEMM ====================
// C[M,N] fp32 = (Ah+Al)[M,K] @ (Bh+Bl)[K,N], B given transposed [N][K].
// 128x128 tile, BK=32, 256 threads = 4 waves in 2x2, each wave 64x64
// (4x4 frags of 16x16x32). 3 MFMA per frag pair: AhBh + AhBl + AlBh.
__global__ __launch_bounds__(256) void k_gemm_bf16(
    const short* __restrict__ Ah, const short* __restrict__ Al,   // [MPAD][K]
    const short* __restrict__ Bth, const short* __restrict__ Btl, // [N][K]
    float* __restrict__ C, int M, int N, int K) {
  __shared__ __align__(16) short As_h[128 * 32];
  __shared__ __align__(16) short As_l[128 * 32];
  __shared__ __align__(16) short Bs_h[128 * 32];
  __shared__ __align__(16) short Bs_l[128 * 32];

  const int tid = threadIdx.x;
  const int w = tid >> 6;
  const int l = tid & 63;
  const int wr = w >> 1, wc = w & 1;
  const int row0 = blockIdx.y * 128;
  const int col0 = blockIdx.x * 128;

  const int lr = l >> 2;         // staging: lane's row within 16-row slab
  const int lco = (l & 3) * 8;   // staging: lane's k offset (8 bf16 = 16B)

  f32x4 acc[4][4];
#pragma unroll
  for (int i = 0; i < 4; ++i)
#pragma unroll
    for (int j = 0; j < 4; ++j) acc[i][j] = (f32x4){0.f, 0.f, 0.f, 0.f};

  const int fr = l & 15;        // frag row/col within 16
  const int fk = (l >> 4) * 8;  // frag k offset

  for (int k0 = 0; k0 < K; k0 += 32) {
    // ---- stage 4 tiles (A hi/lo, Bt hi/lo), each 128x32 bf16, via
    // global_load_lds width 16. Wave w stages rows [q*64+w*16, +16). ----
#pragma unroll
    for (int q = 0; q < 2; ++q) {
      int r = q * 64 + w * 16;   // wave-uniform
      int gr = r + lr;           // per-lane row within tile
      gload16(Ah  + (size_t)(row0 + gr) * K + k0 + lco, &As_h[r * 32]);
      gload16(Al  + (size_t)(row0 + gr) * K + k0 + lco, &As_l[r * 32]);
      gload16(Bth + (size_t)(col0 + gr) * K + k0 + lco, &Bs_h[r * 32]);
      gload16(Btl + (size_t)(col0 + gr) * K + k0 + lco, &Bs_l[r * 32]);
    }
    __syncthreads();

    bf16x8 ah[4], al_[4], bh[4], bl_[4];
#pragma unroll
    for (int m = 0; m < 4; ++m) {
      int ar = wr * 64 + m * 16 + fr;
      ah[m]  = *(const bf16x8*)&As_h[ar * 32 + fk];
      al_[m] = *(const bf16x8*)&As_l[ar * 32 + fk];
      int bc = wc * 64 + m * 16 + fr;
      bh[m]  = *(const bf16x8*)&Bs_h[bc * 32 + fk];
      bl_[m] = *(const bf16x8*)&Bs_l[bc * 32 + fk];
    }
#pragma unroll
    for (int m = 0; m < 4; ++m)
#pragma unroll
      for (int n = 0; n < 4; ++n) {
        acc[m][n] = __builtin_amdgcn_mfma_f32_16x16x32_bf16(ah[m],  bh[n],  acc[m][n], 0, 0, 0);
        acc[m][n] = __builtin_amdgcn_mfma_f32_16x16x32_bf16(ah[m],  bl_[n], acc[m][n], 0, 0, 0);
        acc[m][n] = __builtin_amdgcn_mfma_f32_16x16x32_bf16(al_[m], bh[n],  acc[m][n], 0, 0, 0);
      }
    __syncthreads();
  }

  // epilogue: D[i][j], lane l reg r -> row (l>>4)*4+r, col l&15
#pragma unroll
  for (int m = 0; m < 4; ++m) {
#pragma unroll
    for (int i = 0; i < 4; ++i) {
      int row = row0 + wr * 64 + m * 16 + (l >> 4) * 4 + i;
      if (row < M) {
#pragma unroll
        for (int n = 0; n < 4; ++n)
          C[(size_t)row * N + col0 + wc * 64 + n * 16 + (l & 15)] = acc[m][n][i];
      }
    }
  }
}

// ======================= per-node alpha dots =======================

__global__ void k_alpha(const float* __restrict__ h,
                        const float* __restrict__ a_src,
                        const float* __restrict__ a_dst,
                        float* __restrict__ asrc, float* __restrict__ adst,
                        int H) {
  const int C = HIDC;
  int n = blockIdx.x;
  int w = threadIdx.x >> 6;
  int l = threadIdx.x & 63;
  const float* hr = h + (size_t)n * H * C + w * C;
  float h0 = hr[l], h1 = hr[l + 64];
  float s1 = h0 * a_src[w * C + l] + h1 * a_src[w * C + l + 64];
  float s2 = h0 * a_dst[w * C + l] + h1 * a_dst[w * C + l + 64];
#pragma unroll
  for (int off = 32; off; off >>= 1) {
    s1 += __shfl_xor(s1, off);
    s2 += __shfl_xor(s2, off);
  }
  if (l == 0) {
    asrc[n * H + w] = s1;
    adst[n * H + w] = s2;
  }
}

// ========================= GAT aggregation =========================
// bf16out=1: write (hi,lo) bf16 pair (feeds next split-bf16 GEMM)
// bf16out=0: write fp32 to outf
__global__ void k_aggregate(const float* __restrict__ h,
                            const float* __restrict__ asrc,
                            const float* __restrict__ adst,
                            const int* __restrict__ row_ptr,
                            const int* __restrict__ col,
                            const float* __restrict__ bias,
                            float* __restrict__ outf,
                            short* __restrict__ oh, short* __restrict__ ol,
                            int H, int applyElu, int bf16out) {
  const int C = HIDC;
  int n = blockIdx.x;
  int w = threadIdx.x >> 6;
  int l = threadIdx.x & 63;
  int HC = H * C;
  int r0 = row_ptr[n], r1 = row_ptr[n + 1];
  float adn = adst[n * H + w];

  float m = -INFINITY;
  for (int j = r0 + l; j < r1; j += 64) {
    int s = col[j];
    float e = asrc[s * H + w] + adn;
    e = e > 0.f ? e : NEG_SLOPE * e;
    m = fmaxf(m, e);
  }
#pragma unroll
  for (int off = 32; off; off >>= 1) m = fmaxf(m, __shfl_xor(m, off));

  float acc0 = 0.f, acc1 = 0.f, ssum = 0.f;
  for (int j = r0; j < r1; ++j) {
    int s = col[j];
    float e = asrc[s * H + w] + adn;
    e = e > 0.f ? e : NEG_SLOPE * e;
    float p = __expf(e - m);
    ssum += p;
    const float* hr = h + (size_t)s * HC + w * C;
    acc0 += p * hr[l];
    acc1 += p * hr[l + 64];
  }
  float inv = 1.f / (ssum + 1e-16f);
  float o0 = acc0 * inv + bias[w * C + l];
  float o1 = acc1 * inv + bias[w * C + l + 64];
  if (applyElu) {
    o0 = o0 > 0.f ? o0 : (__expf(o0) - 1.f);
    o1 = o1 > 0.f ? o1 : (__expf(o1) - 1.f);
  }
  size_t i0 = (size_t)n * HC + w * C + l;
  size_t i1 = i0 + 64;
  if (bf16out) {
    unsigned short h0 = bf16hi(o0);
    float hf0 = __uint_as_float((unsigned)h0 << 16);
    oh[i0] = (short)h0;
    ol[i0] = (short)bf16hi(o0 - hf0);
    unsigned short h1 = bf16hi(o1);
    float hf1 = __uint_as_float((unsigned)h1 << 16);
    oh[i1] = (short)h1;
    ol[i1] = (short)bf16hi(o1 - hf1);
  } else {
    outf[i0] = o0;
    outf[i1] = o1;
  }
}

// ============================ launcher ============================

extern "C" void kernel_launch(void* const* d_in, const int* in_sizes, int n_in,
                              void* d_out, int out_size, void* d_ws, size_t ws_size,
                              hipStream_t stream) {
  const float* x      = (const float*)d_in[0];
  const int*   ei     = (const int*)d_in[1];
  const float* W1     = (const float*)d_in[2];
  const float* a1_src = (const float*)d_in[3];
  const float* a1_dst = (const float*)d_in[4];
  const float* b1     = (const float*)d_in[5];
  const float* W2     = (const float*)d_in[6];
  const float* a2_src = (const float*)d_in[7];
  const float* a2_dst = (const float*)d_in[8];
  const float* b2     = (const float*)d_in[9];
  const float* W3     = (const float*)d_in[10];
  const float* a3_src = (const float*)d_in[11];
  const float* a3_dst = (const float*)d_in[12];
  const float* b3     = (const float*)d_in[13];
  float* out = (float*)d_out;

  char* ws = (char*)d_ws;
  size_t off = 0;
  auto alloc = [&](size_t bytes) {
    size_t r = off;
    off = (off + bytes + 255) & ~(size_t)255;
    return r;
  };
  // A-side hi/lo buffers, padded to MPAD rows. Reused: layer-1 input (x) and
  // then layer-1/2 aggregate outputs. Sized for the larger (K=768).
  short* Aih = (short*)(ws + alloc((size_t)MPAD * INC * 2));
  short* Ail = (short*)(ws + alloc((size_t)MPAD * INC * 2));
  // transposed weight hi/lo
  short* w1h = (short*)(ws + alloc((size_t)512 * INC * 2));
  short* w1l = (short*)(ws + alloc((size_t)512 * INC * 2));
  short* w2h = (short*)(ws + alloc((size_t)512 * 512 * 2));
  short* w2l = (short*)(ws + alloc((size_t)512 * 512 * 2));
  short* w3h = (short*)(ws + alloc((size_t)128 * 512 * 2));
  short* w3l = (short*)(ws + alloc((size_t)128 * 512 * 2));
  float* hA      = (float*)(ws + alloc((size_t)NNODES * 512 * 4));
  float* asrc    = (float*)(ws + alloc((size_t)NNODES * NHEADS * 4));
  float* adst    = (float*)(ws + alloc((size_t)NNODES * NHEADS * 4));
  int*   row_ptr = (int*)(ws + alloc((size_t)(NNODES + 1) * 4));
  int*   fill    = (int*)(ws + alloc((size_t)NNODES * 4));
  int*   cnt     = (int*)(ws + alloc((size_t)NNODES * 4));
  int*   colv    = (int*)(ws + alloc((size_t)(NEDGES + NNODES) * 4));

  const int TOT = NEDGES + NNODES;

  // ---- CSR build ----
  k_zero<<<(NNODES + 255) / 256, 256, 0, stream>>>(cnt, NNODES);
  k_count<<<(TOT + 255) / 256, 256, 0, stream>>>(ei, cnt);
  k_scan<<<1, 1024, 0, stream>>>(cnt, row_ptr, fill);
  k_fill<<<(TOT + 255) / 256, 256, 0, stream>>>(ei, fill, colv);

  // ---- decompose inputs & weights ----
  k_decomp<<<(NNODES * INC + 255) / 256, 256, 0, stream>>>(x, Aih, Ail, NNODES * INC);
  k_decomp_wt<<<dim3(512 / 32, INC / 32), 256, 0, stream>>>(W1, w1h, w1l, INC, 512);
  k_decomp_wt<<<dim3(512 / 32, 512 / 32), 256, 0, stream>>>(W2, w2h, w2l, 512, 512);
  k_decomp_wt<<<dim3(128 / 32, 512 / 32), 256, 0, stream>>>(W3, w3h, w3l, 512, 128);

  const int GY = MPAD / 128;  // 157

  // ---- layer 1: 768 -> 4x128, concat, ELU ----
  k_gemm_bf16<<<dim3(512 / 128, GY), 256, 0, stream>>>(Aih, Ail, w1h, w1l, hA,
                                                       NNODES, 512, INC);
  k_alpha<<<NNODES, NHEADS * 64, 0, stream>>>(hA, a1_src, a1_dst, asrc, adst, NHEADS);
  k_aggregate<<<NNODES, NHEADS * 64, 0, stream>>>(hA, asrc, adst, row_ptr, colv,
                                                  b1, nullptr, Aih, Ail, NHEADS, 1, 1);

  // ---- layer 2: 512 -> 4x128, concat, ELU ----
  k_gemm_bf16<<<dim3(512 / 128, GY), 256, 0, stream>>>(Aih, Ail, w2h, w2l, hA,
                                                       NNODES, 512, 512);
  k_alpha<<<NNODES, NHEADS * 64, 0, stream>>>(hA, a2_src, a2_dst, asrc, adst, NHEADS);
  k_aggregate<<<NNODES, NHEADS * 64, 0, stream>>>(hA, asrc, adst, row_ptr, colv,
                                                  b2, nullptr, Aih, Ail, NHEADS, 1, 1);

  // ---- layer 3: 512 -> 128, 1 head, no ELU, fp32 out ----
  k_gemm_bf16<<<dim3(1, GY), 256, 0, stream>>>(Aih, Ail, w3h, w3l, hA,
                                               NNODES, 128, 512);
  k_alpha<<<NNODES, 64, 0, stream>>>(hA, a3_src, a3_dst, asrc, adst, 1);
  k_aggregate<<<NNODES, 64, 0, stream>>>(hA, asrc, adst, row_ptr, colv,
                                         b3, out, nullptr, nullptr, 1, 0, 0);
}

// Round 4
// 642.119 us; speedup vs baseline: 1.4193x; 1.0403x over previous
//
#include <hip/hip_runtime.h>
#include <hip/hip_fp16.h>
#include <math.h>

#define NNODES 20000
#define MPAD   20096   // NNODES rounded up to 128
#define NEDGES 400000
#define INC    768
#define HIDC   128
#define NHEADS 4
#define NEG_SLOPE 0.2f

typedef __attribute__((ext_vector_type(8))) short bf16x8;
typedef __attribute__((ext_vector_type(4))) float f32x4;

// round-to-nearest-even fp32 -> bf16 (bits)
__device__ __forceinline__ unsigned short bf16hi(float v) {
  unsigned u = __float_as_uint(v);
  return (unsigned short)((u + 0x7fffu + ((u >> 16) & 1u)) >> 16);
}

__device__ __forceinline__ void gload16(const void* g, void* l) {
  __builtin_amdgcn_global_load_lds(
      (const __attribute__((address_space(1))) unsigned int*)g,
      (__attribute__((address_space(3))) unsigned int*)l, 16, 0, 0);
}

// ============================ CSR build ============================

__global__ void k_zero(int* __restrict__ p, int n) {
  int i = blockIdx.x * blockDim.x + threadIdx.x;
  if (i < n) p[i] = 0;
}

__global__ void k_count(const int* __restrict__ ei, int* __restrict__ cnt) {
  int i = blockIdx.x * blockDim.x + threadIdx.x;
  const int tot = NEDGES + NNODES;
  if (i >= tot) return;
  int dst = (i < NEDGES) ? ei[NEDGES + i] : (i - NEDGES);
  atomicAdd(&cnt[dst], 1);
}

__global__ void k_scan(const int* __restrict__ cnt, int* __restrict__ row_ptr,
                       int* __restrict__ fill) {
  __shared__ int part[1024];
  int t = threadIdx.x;
  const int chunk = (NNODES + 1023) / 1024;
  int lo = t * chunk, hi = min(lo + chunk, NNODES);
  int s = 0;
  for (int i = lo; i < hi; ++i) s += cnt[i];
  part[t] = s;
  __syncthreads();
  for (int off = 1; off < 1024; off <<= 1) {
    int v = (t >= off) ? part[t - off] : 0;
    __syncthreads();
    part[t] += v;
    __syncthreads();
  }
  int pref = (t == 0) ? 0 : part[t - 1];
  for (int i = lo; i < hi; ++i) {
    row_ptr[i] = pref;
    fill[i] = pref;
    pref += cnt[i];
  }
  if (t == 1023) row_ptr[NNODES] = part[1023];
}

__global__ void k_fill(const int* __restrict__ ei, int* __restrict__ fill,
                       int* __restrict__ col) {
  int i = blockIdx.x * blockDim.x + threadIdx.x;
  const int tot = NEDGES + NNODES;
  if (i >= tot) return;
  int srcv, dstv;
  if (i < NEDGES) { srcv = ei[i]; dstv = ei[NEDGES + i]; }
  else            { srcv = i - NEDGES; dstv = srcv; }
  int pos = atomicAdd(&fill[dstv], 1);
  col[pos] = srcv;
}

// ========================= decompose kernels =========================

__global__ void k_decomp(const float* __restrict__ in, short* __restrict__ hi,
                         short* __restrict__ lo, int n) {
  int i = blockIdx.x * blockDim.x + threadIdx.x;
  if (i >= n) return;
  float v = in[i];
  unsigned short h = bf16hi(v);
  float hf = __uint_as_float((unsigned)h << 16);
  hi[i] = (short)h;
  lo[i] = (short)bf16hi(v - hf);
}

// W [K][N] fp32 -> W^T hi/lo [N][K] bf16 (LDS-tiled transpose)
__global__ __launch_bounds__(256) void k_decomp_wt(
    const float* __restrict__ W, short* __restrict__ th, short* __restrict__ tl,
    int K, int N) {
  __shared__ float t[32][33];
  int bn = blockIdx.x, bk = blockIdx.y;
  int tx = threadIdx.x & 31, ty = threadIdx.x >> 5;  // 32 x 8
#pragma unroll
  for (int r = 0; r < 4; ++r)
    t[ty + r * 8][tx] = W[(size_t)(bk * 32 + ty + r * 8) * N + bn * 32 + tx];
  __syncthreads();
#pragma unroll
  for (int r = 0; r < 4; ++r) {
    int n = bn * 32 + ty + r * 8;
    int k = bk * 32 + tx;
    float v = t[tx][ty + r * 8];
    unsigned short h = bf16hi(v);
    float hf = __uint_as_float((unsigned)h << 16);
    th[(size_t)n * K + k] = (short)h;
    tl[(size_t)n * K + k] = (short)bf16hi(v - hf);
  }
}

// ==================== split-bf16 MFMA GEMM + fused alpha ====================
// C[M,N] = (Ah+Al)[M,K] @ (Bh+Bl)[K,N], B transposed [N][K]. 128x128 tile,
// BK=32, 4 waves 2x2, each wave 64x64 (4x4 frags of 16x16x32).
// 3 MFMA per frag: AhBh + AhBl + AlBh.
// Each col-block == one head: epilogue computes alpha_src/alpha_dst for its
// 128 rows from the exact fp32 accumulators.
// Output: fp16 Ch (layers 1/2) or fp32 Cf (layer 3).
__global__ __launch_bounds__(256) void k_gemm_bf16(
    const short* __restrict__ Ah, const short* __restrict__ Al,
    const short* __restrict__ Bth, const short* __restrict__ Btl,
    float* __restrict__ Cf, __half* __restrict__ Ch,
    const float* __restrict__ av_s, const float* __restrict__ av_d,
    float* __restrict__ asrcO, float* __restrict__ adstO,
    int M, int N, int K, int H) {
  __shared__ __align__(16) short As_h[128 * 32];
  __shared__ __align__(16) short As_l[128 * 32];
  __shared__ __align__(16) short Bs_h[128 * 32];
  __shared__ __align__(16) short Bs_l[128 * 32];
  __shared__ float red1[128][2];
  __shared__ float red2[128][2];

  const int tid = threadIdx.x;
  const int w = tid >> 6;
  const int l = tid & 63;
  const int wr = w >> 1, wc = w & 1;
  const int row0 = blockIdx.y * 128;
  const int col0 = blockIdx.x * 128;
  const int hd = col0 >> 7;

  const int lr = l >> 2;
  const int lco = (l & 3) * 8;

  f32x4 acc[4][4];
#pragma unroll
  for (int i = 0; i < 4; ++i)
#pragma unroll
    for (int j = 0; j < 4; ++j) acc[i][j] = (f32x4){0.f, 0.f, 0.f, 0.f};

  const int fr = l & 15;
  const int fk = (l >> 4) * 8;

  for (int k0 = 0; k0 < K; k0 += 32) {
#pragma unroll
    for (int q = 0; q < 2; ++q) {
      int r = q * 64 + w * 16;   // wave-uniform LDS row base
      int gr = r + lr;           // per-lane global row within tile
      gload16(Ah  + (size_t)(row0 + gr) * K + k0 + lco, &As_h[r * 32]);
      gload16(Al  + (size_t)(row0 + gr) * K + k0 + lco, &As_l[r * 32]);
      gload16(Bth + (size_t)(col0 + gr) * K + k0 + lco, &Bs_h[r * 32]);
      gload16(Btl + (size_t)(col0 + gr) * K + k0 + lco, &Bs_l[r * 32]);
    }
    __syncthreads();

    bf16x8 ah[4], al_[4], bh[4], bl_[4];
#pragma unroll
    for (int m = 0; m < 4; ++m) {
      int ar = wr * 64 + m * 16 + fr;
      ah[m]  = *(const bf16x8*)&As_h[ar * 32 + fk];
      al_[m] = *(const bf16x8*)&As_l[ar * 32 + fk];
      int bc = wc * 64 + m * 16 + fr;
      bh[m]  = *(const bf16x8*)&Bs_h[bc * 32 + fk];
      bl_[m] = *(const bf16x8*)&Bs_l[bc * 32 + fk];
    }
#pragma unroll
    for (int m = 0; m < 4; ++m)
#pragma unroll
      for (int n = 0; n < 4; ++n) {
        acc[m][n] = __builtin_amdgcn_mfma_f32_16x16x32_bf16(ah[m],  bh[n],  acc[m][n], 0, 0, 0);
        acc[m][n] = __builtin_amdgcn_mfma_f32_16x16x32_bf16(ah[m],  bl_[n], acc[m][n], 0, 0, 0);
        acc[m][n] = __builtin_amdgcn_mfma_f32_16x16x32_bf16(al_[m], bh[n],  acc[m][n], 0, 0, 0);
      }
    __syncthreads();
  }

  // ---- fused alpha: s1[row] = sum_c h[row][c]*a_src[hd][c], s2 likewise ----
  const float* as_v = av_s + hd * HIDC;
  const float* ad_v = av_d + hd * HIDC;
#pragma unroll
  for (int m = 0; m < 4; ++m)
#pragma unroll
    for (int i = 0; i < 4; ++i) {
      float s1 = 0.f, s2 = 0.f;
#pragma unroll
      for (int n = 0; n < 4; ++n) {
        int c = wc * 64 + n * 16 + (l & 15);
        float v = acc[m][n][i];
        s1 += v * as_v[c];
        s2 += v * ad_v[c];
      }
#pragma unroll
      for (int off = 1; off < 16; off <<= 1) {
        s1 += __shfl_xor(s1, off);
        s2 += __shfl_xor(s2, off);
      }
      if ((l & 15) == 0) {
        int rl = wr * 64 + m * 16 + (l >> 4) * 4 + i;
        red1[rl][wc] = s1;
        red2[rl][wc] = s2;
      }
    }
  __syncthreads();
  if (tid < 128) {
    int row = row0 + tid;
    if (row < M) {
      asrcO[row * H + hd] = red1[tid][0] + red1[tid][1];
      adstO[row * H + hd] = red2[tid][0] + red2[tid][1];
    }
  }

  // ---- C write: D row=(l>>4)*4+i, col=l&15 within frag (m,n) ----
#pragma unroll
  for (int m = 0; m < 4; ++m) {
#pragma unroll
    for (int i = 0; i < 4; ++i) {
      int row = row0 + wr * 64 + m * 16 + (l >> 4) * 4 + i;
      if (row < M) {
#pragma unroll
        for (int n = 0; n < 4; ++n) {
          int colg = col0 + wc * 64 + n * 16 + (l & 15);
          if (Ch) Ch[(size_t)row * N + colg] = __float2half(acc[m][n][i]);
          else    Cf[(size_t)row * N + colg] = acc[m][n][i];
        }
      }
    }
  }
}

// ================== GAT aggregation, fp16 gather (layers 1/2) ==================
// block = 256 (4 waves); wave w = head w; lane l owns channels 2l, 2l+1.
// Output: bf16 hi/lo pair (feeds next split-bf16 GEMM), with ELU.
__global__ __launch_bounds__(256) void k_aggregate16(
    const __half* __restrict__ h16,   // [N][512]
    const float* __restrict__ asrc, const float* __restrict__ adst,
    const int* __restrict__ row_ptr, const int* __restrict__ col,
    const float* __restrict__ bias,   // [512]
    short* __restrict__ oh, short* __restrict__ ol) {
  int n = blockIdx.x;
  int w = threadIdx.x >> 6;
  int l = threadIdx.x & 63;
  int r0 = row_ptr[n], r1 = row_ptr[n + 1];
  float adn = adst[n * NHEADS + w];

  // pass 1: per-head max
  float m = -INFINITY;
  for (int j = r0 + l; j < r1; j += 64) {
    int s = col[j];
    float e = asrc[s * NHEADS + w] + adn;
    e = e > 0.f ? e : NEG_SLOPE * e;
    m = fmaxf(m, e);
  }
#pragma unroll
  for (int off = 32; off; off >>= 1) m = fmaxf(m, __shfl_xor(m, off));

  // pass 2: exp-weighted accumulation
  float acc0 = 0.f, acc1 = 0.f, ssum = 0.f;
  for (int j = r0; j < r1; ++j) {
    int s = col[j];
    float e = asrc[s * NHEADS + w] + adn;
    e = e > 0.f ? e : NEG_SLOPE * e;
    float p = __expf(e - m);
    ssum += p;
    __half2 hh = *((const __half2*)(h16 + (size_t)s * 512 + w * 128) + l);
    float2 hv = __half22float2(hh);
    acc0 += p * hv.x;
    acc1 += p * hv.y;
  }
  float inv = 1.f / (ssum + 1e-16f);
  int c0 = w * 128 + 2 * l;
  float o0 = acc0 * inv + bias[c0];
  float o1 = acc1 * inv + bias[c0 + 1];
  o0 = o0 > 0.f ? o0 : (__expf(o0) - 1.f);  // ELU
  o1 = o1 > 0.f ? o1 : (__expf(o1) - 1.f);

  size_t i0 = (size_t)n * 512 + c0;
  unsigned short h0 = bf16hi(o0);
  unsigned short h1 = bf16hi(o1);
  float f0 = __uint_as_float((unsigned)h0 << 16);
  float f1 = __uint_as_float((unsigned)h1 << 16);
  unsigned short l0 = bf16hi(o0 - f0);
  unsigned short l1 = bf16hi(o1 - f1);
  *(unsigned*)(oh + i0) = (unsigned)h0 | ((unsigned)h1 << 16);
  *(unsigned*)(ol + i0) = (unsigned)l0 | ((unsigned)l1 << 16);
}

// ============== GAT aggregation, fp32 (layer 3, final output) ==============
__global__ void k_aggregate(const float* __restrict__ h,     // [N][128]
                            const float* __restrict__ asrc,
                            const float* __restrict__ adst,
                            const int* __restrict__ row_ptr,
                            const int* __restrict__ col,
                            const float* __restrict__ bias,
                            float* __restrict__ outf) {
  const int C = HIDC;
  int n = blockIdx.x;
  int l = threadIdx.x & 63;
  int r0 = row_ptr[n], r1 = row_ptr[n + 1];
  float adn = adst[n];

  float m = -INFINITY;
  for (int j = r0 + l; j < r1; j += 64) {
    int s = col[j];
    float e = asrc[s] + adn;
    e = e > 0.f ? e : NEG_SLOPE * e;
    m = fmaxf(m, e);
  }
#pragma unroll
  for (int off = 32; off; off >>= 1) m = fmaxf(m, __shfl_xor(m, off));

  float acc0 = 0.f, acc1 = 0.f, ssum = 0.f;
  for (int j = r0; j < r1; ++j) {
    int s = col[j];
    float e = asrc[s] + adn;
    e = e > 0.f ? e : NEG_SLOPE * e;
    float p = __expf(e - m);
    ssum += p;
    const float* hr = h + (size_t)s * C;
    acc0 += p * hr[l];
    acc1 += p * hr[l + 64];
  }
  float inv = 1.f / (ssum + 1e-16f);
  outf[(size_t)n * C + l]      = acc0 * inv + bias[l];
  outf[(size_t)n * C + l + 64] = acc1 * inv + bias[l + 64];
}

// ============================ launcher ============================

extern "C" void kernel_launch(void* const* d_in, const int* in_sizes, int n_in,
                              void* d_out, int out_size, void* d_ws, size_t ws_size,
                              hipStream_t stream) {
  const float* x      = (const float*)d_in[0];
  const int*   ei     = (const int*)d_in[1];
  const float* W1     = (const float*)d_in[2];
  const float* a1_src = (const float*)d_in[3];
  const float* a1_dst = (const float*)d_in[4];
  const float* b1     = (const float*)d_in[5];
  const float* W2     = (const float*)d_in[6];
  const float* a2_src = (const float*)d_in[7];
  const float* a2_dst = (const float*)d_in[8];
  const float* b2     = (const float*)d_in[9];
  const float* W3     = (const float*)d_in[10];
  const float* a3_src = (const float*)d_in[11];
  const float* a3_dst = (const float*)d_in[12];
  const float* b3     = (const float*)d_in[13];
  float* out = (float*)d_out;

  char* ws = (char*)d_ws;
  size_t off = 0;
  auto alloc = [&](size_t bytes) {
    size_t r = off;
    off = (off + bytes + 255) & ~(size_t)255;
    return r;
  };
  short* Aih = (short*)(ws + alloc((size_t)MPAD * INC * 2));
  short* Ail = (short*)(ws + alloc((size_t)MPAD * INC * 2));
  short* w1h = (short*)(ws + alloc((size_t)512 * INC * 2));
  short* w1l = (short*)(ws + alloc((size_t)512 * INC * 2));
  short* w2h = (short*)(ws + alloc((size_t)512 * 512 * 2));
  short* w2l = (short*)(ws + alloc((size_t)512 * 512 * 2));
  short* w3h = (short*)(ws + alloc((size_t)128 * 512 * 2));
  short* w3l = (short*)(ws + alloc((size_t)128 * 512 * 2));
  __half* h16    = (__half*)(ws + alloc((size_t)MPAD * 512 * 2));
  float* hA      = (float*)(ws + alloc((size_t)NNODES * HIDC * 4));
  float* asrc    = (float*)(ws + alloc((size_t)NNODES * NHEADS * 4));
  float* adst    = (float*)(ws + alloc((size_t)NNODES * NHEADS * 4));
  int*   row_ptr = (int*)(ws + alloc((size_t)(NNODES + 1) * 4));
  int*   fill    = (int*)(ws + alloc((size_t)NNODES * 4));
  int*   cnt     = (int*)(ws + alloc((size_t)NNODES * 4));
  int*   colv    = (int*)(ws + alloc((size_t)(NEDGES + NNODES) * 4));

  const int TOT = NEDGES + NNODES;

  // ---- CSR build ----
  k_zero<<<(NNODES + 255) / 256, 256, 0, stream>>>(cnt, NNODES);
  k_count<<<(TOT + 255) / 256, 256, 0, stream>>>(ei, cnt);
  k_scan<<<1, 1024, 0, stream>>>(cnt, row_ptr, fill);
  k_fill<<<(TOT + 255) / 256, 256, 0, stream>>>(ei, fill, colv);

  // ---- decompose inputs & weights ----
  k_decomp<<<(NNODES * INC + 255) / 256, 256, 0, stream>>>(x, Aih, Ail, NNODES * INC);
  k_decomp_wt<<<dim3(512 / 32, INC / 32), 256, 0, stream>>>(W1, w1h, w1l, INC, 512);
  k_decomp_wt<<<dim3(512 / 32, 512 / 32), 256, 0, stream>>>(W2, w2h, w2l, 512, 512);
  k_decomp_wt<<<dim3(128 / 32, 512 / 32), 256, 0, stream>>>(W3, w3h, w3l, 512, 128);

  const int GY = MPAD / 128;  // 157

  // ---- layer 1: 768 -> 4x128, concat, ELU ----
  k_gemm_bf16<<<dim3(512 / 128, GY), 256, 0, stream>>>(
      Aih, Ail, w1h, w1l, nullptr, h16, a1_src, a1_dst, asrc, adst,
      NNODES, 512, INC, NHEADS);
  k_aggregate16<<<NNODES, 256, 0, stream>>>(h16, asrc, adst, row_ptr, colv,
                                            b1, Aih, Ail);

  // ---- layer 2: 512 -> 4x128, concat, ELU ----
  k_gemm_bf16<<<dim3(512 / 128, GY), 256, 0, stream>>>(
      Aih, Ail, w2h, w2l, nullptr, h16, a2_src, a2_dst, asrc, adst,
      NNODES, 512, 512, NHEADS);
  k_aggregate16<<<NNODES, 256, 0, stream>>>(h16, asrc, adst, row_ptr, colv,
                                            b2, Aih, Ail);

  // ---- layer 3: 512 -> 128, 1 head, fp32 out ----
  k_gemm_bf16<<<dim3(1, GY), 256, 0, stream>>>(
      Aih, Ail, w3h, w3l, hA, nullptr, a3_src, a3_dst, asrc, adst,
      NNODES, 128, 512, 1);
  k_aggregate<<<NNODES, 64, 0, stream>>>(hA, asrc, adst, row_ptr, colv, b3, out);
}

// Round 6
// 558.089 us; speedup vs baseline: 1.6330x; 1.1506x over previous
//
#include <hip/hip_runtime.h>
#include <hip/hip_fp16.h>
#include <math.h>

#define NNODES 20000
#define MPAD   20096   // NNODES rounded up to 128
#define NEDGES 400000
#define INC    768
#define HIDC   128
#define NHEADS 4
#define NEG_SLOPE 0.2f
#define DEGCAP 512     // per-head LDS cache of edge weights

typedef __attribute__((ext_vector_type(8))) short bf16x8;
typedef __attribute__((ext_vector_type(4))) float f32x4;

// round-to-nearest-even fp32 -> bf16 (bits)
__device__ __forceinline__ unsigned short bf16hi(float v) {
  unsigned u = __float_as_uint(v);
  return (unsigned short)((u + 0x7fffu + ((u >> 16) & 1u)) >> 16);
}

__device__ __forceinline__ void gload16(const void* g, void* l) {
  __builtin_amdgcn_global_load_lds(
      (const __attribute__((address_space(1))) unsigned int*)g,
      (__attribute__((address_space(3))) unsigned int*)l, 16, 0, 0);
}

// ============================ CSR build ============================

__global__ void k_zero(int* __restrict__ p, int n) {
  int i = blockIdx.x * blockDim.x + threadIdx.x;
  if (i < n) p[i] = 0;
}

__global__ void k_count(const int* __restrict__ ei, int* __restrict__ cnt) {
  int i = blockIdx.x * blockDim.x + threadIdx.x;
  const int tot = NEDGES + NNODES;
  if (i >= tot) return;
  int dst = (i < NEDGES) ? ei[NEDGES + i] : (i - NEDGES);
  atomicAdd(&cnt[dst], 1);
}

__global__ void k_scan(const int* __restrict__ cnt, int* __restrict__ row_ptr,
                       int* __restrict__ fill) {
  __shared__ int part[1024];
  int t = threadIdx.x;
  const int chunk = (NNODES + 1023) / 1024;
  int lo = t * chunk, hi = min(lo + chunk, NNODES);
  int s = 0;
  for (int i = lo; i < hi; ++i) s += cnt[i];
  part[t] = s;
  __syncthreads();
  for (int off = 1; off < 1024; off <<= 1) {
    int v = (t >= off) ? part[t - off] : 0;
    __syncthreads();
    part[t] += v;
    __syncthreads();
  }
  int pref = (t == 0) ? 0 : part[t - 1];
  for (int i = lo; i < hi; ++i) {
    row_ptr[i] = pref;
    fill[i] = pref;
    pref += cnt[i];
  }
  if (t == 1023) row_ptr[NNODES] = part[1023];
}

__global__ void k_fill(const int* __restrict__ ei, int* __restrict__ fill,
                       int* __restrict__ col) {
  int i = blockIdx.x * blockDim.x + threadIdx.x;
  const int tot = NEDGES + NNODES;
  if (i >= tot) return;
  int srcv, dstv;
  if (i < NEDGES) { srcv = ei[i]; dstv = ei[NEDGES + i]; }
  else            { srcv = i - NEDGES; dstv = srcv; }
  int pos = atomicAdd(&fill[dstv], 1);
  col[pos] = srcv;
}

// ========================= decompose kernels =========================

__global__ void k_decomp(const float* __restrict__ in, short* __restrict__ hi,
                         short* __restrict__ lo, int n) {
  int i = blockIdx.x * blockDim.x + threadIdx.x;
  if (i >= n) return;
  float v = in[i];
  unsigned short h = bf16hi(v);
  float hf = __uint_as_float((unsigned)h << 16);
  hi[i] = (short)h;
  lo[i] = (short)bf16hi(v - hf);
}

// W [K][N] fp32 -> W^T hi/lo [N][K] bf16 (LDS-tiled transpose)
__global__ __launch_bounds__(256) void k_decomp_wt(
    const float* __restrict__ W, short* __restrict__ th, short* __restrict__ tl,
    int K, int N) {
  __shared__ float t[32][33];
  int bn = blockIdx.x, bk = blockIdx.y;
  int tx = threadIdx.x & 31, ty = threadIdx.x >> 5;  // 32 x 8
#pragma unroll
  for (int r = 0; r < 4; ++r)
    t[ty + r * 8][tx] = W[(size_t)(bk * 32 + ty + r * 8) * N + bn * 32 + tx];
  __syncthreads();
#pragma unroll
  for (int r = 0; r < 4; ++r) {
    int n = bn * 32 + ty + r * 8;
    int k = bk * 32 + tx;
    float v = t[tx][ty + r * 8];
    unsigned short h = bf16hi(v);
    float hf = __uint_as_float((unsigned)h << 16);
    th[(size_t)n * K + k] = (short)h;
    tl[(size_t)n * K + k] = (short)bf16hi(v - hf);
  }
}

// ==================== split-bf16 MFMA GEMM + fused alpha ====================
__global__ __launch_bounds__(256) void k_gemm_bf16(
    const short* __restrict__ Ah, const short* __restrict__ Al,
    const short* __restrict__ Bth, const short* __restrict__ Btl,
    float* __restrict__ Cf, __half* __restrict__ Ch,
    const float* __restrict__ av_s, const float* __restrict__ av_d,
    float* __restrict__ asrcO, float* __restrict__ adstO,
    int M, int N, int K, int H) {
  __shared__ __align__(16) short As_h[128 * 32];
  __shared__ __align__(16) short As_l[128 * 32];
  __shared__ __align__(16) short Bs_h[128 * 32];
  __shared__ __align__(16) short Bs_l[128 * 32];
  __shared__ float red1[128][2];
  __shared__ float red2[128][2];

  const int tid = threadIdx.x;
  const int w = tid >> 6;
  const int l = tid & 63;
  const int wr = w >> 1, wc = w & 1;
  const int row0 = blockIdx.y * 128;
  const int col0 = blockIdx.x * 128;
  const int hd = col0 >> 7;

  const int lr = l >> 2;
  const int lco = (l & 3) * 8;

  f32x4 acc[4][4];
#pragma unroll
  for (int i = 0; i < 4; ++i)
#pragma unroll
    for (int j = 0; j < 4; ++j) acc[i][j] = (f32x4){0.f, 0.f, 0.f, 0.f};

  const int fr = l & 15;
  const int fk = (l >> 4) * 8;

  for (int k0 = 0; k0 < K; k0 += 32) {
#pragma unroll
    for (int q = 0; q < 2; ++q) {
      int r = q * 64 + w * 16;   // wave-uniform LDS row base
      int gr = r + lr;           // per-lane global row within tile
      gload16(Ah  + (size_t)(row0 + gr) * K + k0 + lco, &As_h[r * 32]);
      gload16(Al  + (size_t)(row0 + gr) * K + k0 + lco, &As_l[r * 32]);
      gload16(Bth + (size_t)(col0 + gr) * K + k0 + lco, &Bs_h[r * 32]);
      gload16(Btl + (size_t)(col0 + gr) * K + k0 + lco, &Bs_l[r * 32]);
    }
    __syncthreads();

    bf16x8 ah[4], al_[4], bh[4], bl_[4];
#pragma unroll
    for (int m = 0; m < 4; ++m) {
      int ar = wr * 64 + m * 16 + fr;
      ah[m]  = *(const bf16x8*)&As_h[ar * 32 + fk];
      al_[m] = *(const bf16x8*)&As_l[ar * 32 + fk];
      int bc = wc * 64 + m * 16 + fr;
      bh[m]  = *(const bf16x8*)&Bs_h[bc * 32 + fk];
      bl_[m] = *(const bf16x8*)&Bs_l[bc * 32 + fk];
    }
#pragma unroll
    for (int m = 0; m < 4; ++m)
#pragma unroll
      for (int n = 0; n < 4; ++n) {
        acc[m][n] = __builtin_amdgcn_mfma_f32_16x16x32_bf16(ah[m],  bh[n],  acc[m][n], 0, 0, 0);
        acc[m][n] = __builtin_amdgcn_mfma_f32_16x16x32_bf16(ah[m],  bl_[n], acc[m][n], 0, 0, 0);
        acc[m][n] = __builtin_amdgcn_mfma_f32_16x16x32_bf16(al_[m], bh[n],  acc[m][n], 0, 0, 0);
      }
    __syncthreads();
  }

  // ---- fused alpha: s1[row] = sum_c h[row][c]*a_src[hd][c], s2 likewise ----
  const float* as_v = av_s + hd * HIDC;
  const float* ad_v = av_d + hd * HIDC;
#pragma unroll
  for (int m = 0; m < 4; ++m)
#pragma unroll
    for (int i = 0; i < 4; ++i) {
      float s1 = 0.f, s2 = 0.f;
#pragma unroll
      for (int n = 0; n < 4; ++n) {
        int c = wc * 64 + n * 16 + (l & 15);
        float v = acc[m][n][i];
        s1 += v * as_v[c];
        s2 += v * ad_v[c];
      }
#pragma unroll
      for (int off = 1; off < 16; off <<= 1) {
        s1 += __shfl_xor(s1, off);
        s2 += __shfl_xor(s2, off);
      }
      if ((l & 15) == 0) {
        int rl = wr * 64 + m * 16 + (l >> 4) * 4 + i;
        red1[rl][wc] = s1;
        red2[rl][wc] = s2;
      }
    }
  __syncthreads();
  if (tid < 128) {
    int row = row0 + tid;
    if (row < M) {
      asrcO[row * H + hd] = red1[tid][0] + red1[tid][1];
      adstO[row * H + hd] = red2[tid][0] + red2[tid][1];
    }
  }

  // ---- C write ----
#pragma unroll
  for (int m = 0; m < 4; ++m) {
#pragma unroll
    for (int i = 0; i < 4; ++i) {
      int row = row0 + wr * 64 + m * 16 + (l >> 4) * 4 + i;
      if (row < M) {
#pragma unroll
        for (int n = 0; n < 4; ++n) {
          int colg = col0 + wc * 64 + n * 16 + (l & 15);
          if (Ch) Ch[(size_t)row * N + colg] = __float2half(acc[m][n][i]);
          else    Cf[(size_t)row * N + colg] = acc[m][n][i];
        }
      }
    }
  }
}

// ================== GAT aggregation, fp16 gather (layers 1/2) ==================
// block = 256 (4 waves); wave w = head w.
// Phase A (lanes over edges): e -> wave-max -> p=exp(e-m) cached in LDS + sum.
// Phase B (lanes over channels): serial edge loop = LDS p + h16 gather + FMA.
__global__ __launch_bounds__(256) void k_aggregate16(
    const __half* __restrict__ h16,   // [N][512]
    const float* __restrict__ asrc, const float* __restrict__ adst,
    const int* __restrict__ row_ptr, const int* __restrict__ col,
    const float* __restrict__ bias,   // [512]
    short* __restrict__ oh, short* __restrict__ ol) {
  __shared__ float p_lds[NHEADS][DEGCAP];
  __shared__ int   s_lds[DEGCAP];

  int n = blockIdx.x;
  int w = threadIdx.x >> 6;
  int l = threadIdx.x & 63;
  int r0 = row_ptr[n], r1 = row_ptr[n + 1];
  int D = r1 - r0;
  float adn = adst[n * NHEADS + w];

  // ---- phase A: per-head max, then p into LDS + sum ----
  float m = -INFINITY;
  for (int jj = l; jj < D; jj += 64) {
    int s = col[r0 + jj];
    if (w == 0 && jj < DEGCAP) s_lds[jj] = s;
    float e = asrc[s * NHEADS + w] + adn;
    e = e > 0.f ? e : NEG_SLOPE * e;
    m = fmaxf(m, e);
    if (jj < DEGCAP) p_lds[w][jj] = e;   // stash raw e; exp after max known
  }
#pragma unroll
  for (int off = 32; off; off >>= 1) m = fmaxf(m, __shfl_xor(m, off));

  float ssum = 0.f;
  for (int jj = l; jj < D; jj += 64) {
    float e;
    if (jj < DEGCAP) e = p_lds[w][jj];
    else {
      int s = col[r0 + jj];
      e = asrc[s * NHEADS + w] + adn;
      e = e > 0.f ? e : NEG_SLOPE * e;
    }
    float p = __expf(e - m);
    ssum += p;
    if (jj < DEGCAP) p_lds[w][jj] = p;
  }
#pragma unroll
  for (int off = 32; off; off >>= 1) ssum += __shfl_xor(ssum, off);
  __syncthreads();  // publish p_lds / s_lds

  // ---- phase B: channel-parallel accumulation ----
  float acc0 = 0.f, acc1 = 0.f;
  int Dc = D < DEGCAP ? D : DEGCAP;
  for (int jj = 0; jj < Dc; ++jj) {
    float p = p_lds[w][jj];
    int s = s_lds[jj];
    __half2 hh = *((const __half2*)(h16 + (size_t)s * 512 + w * 128) + l);
    float2 hv = __half22float2(hh);
    acc0 += p * hv.x;
    acc1 += p * hv.y;
  }
  for (int jj = Dc; jj < D; ++jj) {  // rare overflow path
    int s = col[r0 + jj];
    float e = asrc[s * NHEADS + w] + adn;
    e = e > 0.f ? e : NEG_SLOPE * e;
    float p = __expf(e - m);
    __half2 hh = *((const __half2*)(h16 + (size_t)s * 512 + w * 128) + l);
    float2 hv = __half22float2(hh);
    acc0 += p * hv.x;
    acc1 += p * hv.y;
  }

  float inv = 1.f / (ssum + 1e-16f);
  int c0 = w * 128 + 2 * l;
  float o0 = acc0 * inv + bias[c0];
  float o1 = acc1 * inv + bias[c0 + 1];
  o0 = o0 > 0.f ? o0 : (__expf(o0) - 1.f);  // ELU
  o1 = o1 > 0.f ? o1 : (__expf(o1) - 1.f);

  size_t i0 = (size_t)n * 512 + c0;
  unsigned short h0 = bf16hi(o0);
  unsigned short h1 = bf16hi(o1);
  float f0 = __uint_as_float((unsigned)h0 << 16);
  float f1 = __uint_as_float((unsigned)h1 << 16);
  unsigned short l0 = bf16hi(o0 - f0);
  unsigned short l1 = bf16hi(o1 - f1);
  *(unsigned*)(oh + i0) = (unsigned)h0 | ((unsigned)h1 << 16);
  *(unsigned*)(ol + i0) = (unsigned)l0 | ((unsigned)l1 << 16);
}

// ============== GAT aggregation, fp32 (layer 3, final output) ==============
__global__ void k_aggregate(const float* __restrict__ h,     // [N][128]
                            const float* __restrict__ asrc,
                            const float* __restrict__ adst,
                            const int* __restrict__ row_ptr,
                            const int* __restrict__ col,
                            const float* __restrict__ bias,
                            float* __restrict__ outf) {
  const int C = HIDC;
  int n = blockIdx.x;
  int l = threadIdx.x & 63;
  int r0 = row_ptr[n], r1 = row_ptr[n + 1];
  float adn = adst[n];

  float m = -INFINITY;
  for (int j = r0 + l; j < r1; j += 64) {
    int s = col[j];
    float e = asrc[s] + adn;
    e = e > 0.f ? e : NEG_SLOPE * e;
    m = fmaxf(m, e);
  }
#pragma unroll
  for (int off = 32; off; off >>= 1) m = fmaxf(m, __shfl_xor(m, off));

  float acc0 = 0.f, acc1 = 0.f, ssum = 0.f;
  for (int j = r0; j < r1; ++j) {
    int s = col[j];
    float e = asrc[s] + adn;
    e = e > 0.f ? e : NEG_SLOPE * e;
    float p = __expf(e - m);
    ssum += p;
    const float* hr = h + (size_t)s * C;
    acc0 += p * hr[l];
    acc1 += p * hr[l + 64];
  }
  float inv = 1.f / (ssum + 1e-16f);
  outf[(size_t)n * C + l]      = acc0 * inv + bias[l];
  outf[(size_t)n * C + l + 64] = acc1 * inv + bias[l + 64];
}

// ============================ launcher ============================

extern "C" void kernel_launch(void* const* d_in, const int* in_sizes, int n_in,
                              void* d_out, int out_size, void* d_ws, size_t ws_size,
                              hipStream_t stream) {
  const float* x      = (const float*)d_in[0];
  const int*   ei     = (const int*)d_in[1];
  const float* W1     = (const float*)d_in[2];
  const float* a1_src = (const float*)d_in[3];
  const float* a1_dst = (const float*)d_in[4];
  const float* b1     = (const float*)d_in[5];
  const float* W2     = (const float*)d_in[6];
  const float* a2_src = (const float*)d_in[7];
  const float* a2_dst = (const float*)d_in[8];
  const float* b2     = (const float*)d_in[9];
  const float* W3     = (const float*)d_in[10];
  const float* a3_src = (const float*)d_in[11];
  const float* a3_dst = (const float*)d_in[12];
  const float* b3     = (const float*)d_in[13];
  float* out = (float*)d_out;

  char* ws = (char*)d_ws;
  size_t off = 0;
  auto alloc = [&](size_t bytes) {
    size_t r = off;
    off = (off + bytes + 255) & ~(size_t)255;
    return r;
  };
  short* Aih = (short*)(ws + alloc((size_t)MPAD * INC * 2));
  short* Ail = (short*)(ws + alloc((size_t)MPAD * INC * 2));
  short* w1h = (short*)(ws + alloc((size_t)512 * INC * 2));
  short* w1l = (short*)(ws + alloc((size_t)512 * INC * 2));
  short* w2h = (short*)(ws + alloc((size_t)512 * 512 * 2));
  short* w2l = (short*)(ws + alloc((size_t)512 * 512 * 2));
  short* w3h = (short*)(ws + alloc((size_t)128 * 512 * 2));
  short* w3l = (short*)(ws + alloc((size_t)128 * 512 * 2));
  __half* h16    = (__half*)(ws + alloc((size_t)MPAD * 512 * 2));
  float* hA      = (float*)(ws + alloc((size_t)NNODES * HIDC * 4));
  float* asrc    = (float*)(ws + alloc((size_t)NNODES * NHEADS * 4));
  float* adst    = (float*)(ws + alloc((size_t)NNODES * NHEADS * 4));
  int*   row_ptr = (int*)(ws + alloc((size_t)(NNODES + 1) * 4));
  int*   fill    = (int*)(ws + alloc((size_t)NNODES * 4));
  int*   cnt     = (int*)(ws + alloc((size_t)NNODES * 4));
  int*   colv    = (int*)(ws + alloc((size_t)(NEDGES + NNODES) * 4));

  const int TOT = NEDGES + NNODES;

  // ---- CSR build ----
  k_zero<<<(NNODES + 255) / 256, 256, 0, stream>>>(cnt, NNODES);
  k_count<<<(TOT + 255) / 256, 256, 0, stream>>>(ei, cnt);
  k_scan<<<1, 1024, 0, stream>>>(cnt, row_ptr, fill);
  k_fill<<<(TOT + 255) / 256, 256, 0, stream>>>(ei, fill, colv);

  // ---- decompose inputs & weights ----
  k_decomp<<<(NNODES * INC + 255) / 256, 256, 0, stream>>>(x, Aih, Ail, NNODES * INC);
  k_decomp_wt<<<dim3(512 / 32, INC / 32), 256, 0, stream>>>(W1, w1h, w1l, INC, 512);
  k_decomp_wt<<<dim3(512 / 32, 512 / 32), 256, 0, stream>>>(W2, w2h, w2l, 512, 512);
  k_decomp_wt<<<dim3(128 / 32, 512 / 32), 256, 0, stream>>>(W3, w3h, w3l, 512, 128);

  const int GY = MPAD / 128;  // 157

  // ---- layer 1 ----
  k_gemm_bf16<<<dim3(512 / 128, GY), 256, 0, stream>>>(
      Aih, Ail, w1h, w1l, nullptr, h16, a1_src, a1_dst, asrc, adst,
      NNODES, 512, INC, NHEADS);
  k_aggregate16<<<NNODES, 256, 0, stream>>>(h16, asrc, adst, row_ptr, colv,
                                            b1, Aih, Ail);

  // ---- layer 2 ----
  k_gemm_bf16<<<dim3(512 / 128, GY), 256, 0, stream>>>(
      Aih, Ail, w2h, w2l, nullptr, h16, a2_src, a2_dst, asrc, adst,
      NNODES, 512, 512, NHEADS);
  k_aggregate16<<<NNODES, 256, 0, stream>>>(h16, asrc, adst, row_ptr, colv,
                                            b2, Aih, Ail);

  // ---- layer 3 ----
  k_gemm_bf16<<<dim3(1, GY), 256, 0, stream>>>(
      Aih, Ail, w3h, w3l, hA, nullptr, a3_src, a3_dst, asrc, adst,
      NNODES, 128, 512, 1);
  k_aggregate<<<NNODES, 64, 0, stream>>>(hA, asrc, adst, row_ptr, colv, b3, out);
}

// Round 8
// 531.229 us; speedup vs baseline: 1.7155x; 1.0506x over previous
//
#include <hip/hip_runtime.h>
#include <hip/hip_fp16.h>
#include <math.h>

#define NNODES 20000
#define MPAD   20096   // NNODES rounded up to 128
#define NEDGES 400000
#define INC    768
#define HIDC   128
#define NHEADS 4
#define NEG_SLOPE 0.2f
#define DEGCAP 512     // per-head LDS cache of edge weights

typedef __attribute__((ext_vector_type(8))) short bf16x8;
typedef __attribute__((ext_vector_type(4))) float f32x4;

// round-to-nearest-even fp32 -> bf16 (bits)
__device__ __forceinline__ unsigned short bf16hi(float v) {
  unsigned u = __float_as_uint(v);
  return (unsigned short)((u + 0x7fffu + ((u >> 16) & 1u)) >> 16);
}

__device__ __forceinline__ void gload16(const void* g, void* l) {
  __builtin_amdgcn_global_load_lds(
      (const __attribute__((address_space(1))) unsigned int*)g,
      (__attribute__((address_space(3))) unsigned int*)l, 16, 0, 0);
}

// ============================ CSR build ============================

__global__ void k_zero(int* __restrict__ p, int n) {
  int i = blockIdx.x * blockDim.x + threadIdx.x;
  if (i < n) p[i] = 0;
}

__global__ void k_count(const int* __restrict__ ei, int* __restrict__ cnt) {
  int i = blockIdx.x * blockDim.x + threadIdx.x;
  const int tot = NEDGES + NNODES;
  if (i >= tot) return;
  int dst = (i < NEDGES) ? ei[NEDGES + i] : (i - NEDGES);
  atomicAdd(&cnt[dst], 1);
}

__global__ void k_scan(const int* __restrict__ cnt, int* __restrict__ row_ptr,
                       int* __restrict__ fill) {
  __shared__ int part[1024];
  int t = threadIdx.x;
  const int chunk = (NNODES + 1023) / 1024;
  int lo = t * chunk, hi = min(lo + chunk, NNODES);
  int s = 0;
  for (int i = lo; i < hi; ++i) s += cnt[i];
  part[t] = s;
  __syncthreads();
  for (int off = 1; off < 1024; off <<= 1) {
    int v = (t >= off) ? part[t - off] : 0;
    __syncthreads();
    part[t] += v;
    __syncthreads();
  }
  int pref = (t == 0) ? 0 : part[t - 1];
  for (int i = lo; i < hi; ++i) {
    row_ptr[i] = pref;
    fill[i] = pref;
    pref += cnt[i];
  }
  if (t == 1023) row_ptr[NNODES] = part[1023];
}

__global__ void k_fill(const int* __restrict__ ei, int* __restrict__ fill,
                       int* __restrict__ col) {
  int i = blockIdx.x * blockDim.x + threadIdx.x;
  const int tot = NEDGES + NNODES;
  if (i >= tot) return;
  int srcv, dstv;
  if (i < NEDGES) { srcv = ei[i]; dstv = ei[NEDGES + i]; }
  else            { srcv = i - NEDGES; dstv = srcv; }
  int pos = atomicAdd(&fill[dstv], 1);
  col[pos] = srcv;
}

// ========================= decompose kernels =========================

__global__ void k_decomp(const float* __restrict__ in, short* __restrict__ hi,
                         short* __restrict__ lo, int n) {
  int i = blockIdx.x * blockDim.x + threadIdx.x;
  if (i >= n) return;
  float v = in[i];
  unsigned short h = bf16hi(v);
  float hf = __uint_as_float((unsigned)h << 16);
  hi[i] = (short)h;
  lo[i] = (short)bf16hi(v - hf);
}

// W [K][N] fp32 -> W^T hi/lo [N][K] bf16 (LDS-tiled transpose)
__global__ __launch_bounds__(256) void k_decomp_wt(
    const float* __restrict__ W, short* __restrict__ th, short* __restrict__ tl,
    int K, int N) {
  __shared__ float t[32][33];
  int bn = blockIdx.x, bk = blockIdx.y;
  int tx = threadIdx.x & 31, ty = threadIdx.x >> 5;  // 32 x 8
#pragma unroll
  for (int r = 0; r < 4; ++r)
    t[ty + r * 8][tx] = W[(size_t)(bk * 32 + ty + r * 8) * N + bn * 32 + tx];
  __syncthreads();
#pragma unroll
  for (int r = 0; r < 4; ++r) {
    int n = bn * 32 + ty + r * 8;
    int k = bk * 32 + tx;
    float v = t[tx][ty + r * 8];
    unsigned short h = bf16hi(v);
    float hf = __uint_as_float((unsigned)h << 16);
    th[(size_t)n * K + k] = (short)h;
    tl[(size_t)n * K + k] = (short)bf16hi(v - hf);
  }
}

// ==================== split-bf16 MFMA GEMM + fused alpha ====================
// 2-phase double-buffered staging (prefetch next K-tile during MFMA) +
// bijective chunked XCD swizzle (col-blocks of a row-tile share an XCD L2).
__global__ __launch_bounds__(256) void k_gemm_bf16(
    const short* __restrict__ Ah, const short* __restrict__ Al,
    const short* __restrict__ Bth, const short* __restrict__ Btl,
    float* __restrict__ Cf, __half* __restrict__ Ch,
    const float* __restrict__ av_s, const float* __restrict__ av_d,
    float* __restrict__ asrcO, float* __restrict__ adstO,
    int M, int N, int K, int H) {
  __shared__ __align__(16) short As_h[2][128 * 32];
  __shared__ __align__(16) short As_l[2][128 * 32];
  __shared__ __align__(16) short Bs_h[2][128 * 32];
  __shared__ __align__(16) short Bs_l[2][128 * 32];
  __shared__ float red1[128][2];
  __shared__ float red2[128][2];

  const int tid = threadIdx.x;
  const int w = tid >> 6;
  const int l = tid & 63;
  const int wr = w >> 1, wc = w & 1;

  // ---- bijective chunked XCD swizzle: hw id -> logical tile ----
  const int nwg = gridDim.x * gridDim.y;
  const int h_id = blockIdx.y * gridDim.x + blockIdx.x;
  const int q = nwg >> 3, r8 = nwg & 7;
  const int xcd = h_id & 7, slot = h_id >> 3;
  const int logical = xcd * q + min(xcd, r8) + slot;
  const int by = logical / gridDim.x;
  const int bx = logical - by * gridDim.x;

  const int row0 = by * 128;
  const int col0 = bx * 128;
  const int hd = bx;  // 128 cols per head

  const int lr = l >> 2;         // staging row within 16-row slab
  const int lco = (l & 3) * 8;   // staging k-offset (8 bf16 = 16 B)

  f32x4 acc[4][4];
#pragma unroll
  for (int i = 0; i < 4; ++i)
#pragma unroll
    for (int j = 0; j < 4; ++j) acc[i][j] = (f32x4){0.f, 0.f, 0.f, 0.f};

  const int fr = l & 15;
  const int fk = (l >> 4) * 8;

  auto stage = [&](int buf, int k0) {
#pragma unroll
    for (int qq = 0; qq < 2; ++qq) {
      int rr = qq * 64 + w * 16;   // wave-uniform LDS row base
      int gr = rr + lr;            // per-lane row within tile
      gload16(Ah  + (size_t)(row0 + gr) * K + k0 + lco, &As_h[buf][rr * 32]);
      gload16(Al  + (size_t)(row0 + gr) * K + k0 + lco, &As_l[buf][rr * 32]);
      gload16(Bth + (size_t)(col0 + gr) * K + k0 + lco, &Bs_h[buf][rr * 32]);
      gload16(Btl + (size_t)(col0 + gr) * K + k0 + lco, &Bs_l[buf][rr * 32]);
    }
  };

  // prologue: stage first tile, drain
  stage(0, 0);
  __syncthreads();

  int cur = 0;
  for (int k0 = 0; k0 < K; k0 += 32) {
    // prefetch next K-tile into the other buffer (flies during MFMA below)
    if (k0 + 32 < K) stage(cur ^ 1, k0 + 32);

    bf16x8 ah[4], al_[4], bh[4], bl_[4];
#pragma unroll
    for (int m = 0; m < 4; ++m) {
      int ar = wr * 64 + m * 16 + fr;
      ah[m]  = *(const bf16x8*)&As_h[cur][ar * 32 + fk];
      al_[m] = *(const bf16x8*)&As_l[cur][ar * 32 + fk];
      int bc = wc * 64 + m * 16 + fr;
      bh[m]  = *(const bf16x8*)&Bs_h[cur][bc * 32 + fk];
      bl_[m] = *(const bf16x8*)&Bs_l[cur][bc * 32 + fk];
    }
#pragma unroll
    for (int m = 0; m < 4; ++m)
#pragma unroll
      for (int n = 0; n < 4; ++n) {
        acc[m][n] = __builtin_amdgcn_mfma_f32_16x16x32_bf16(ah[m],  bh[n],  acc[m][n], 0, 0, 0);
        acc[m][n] = __builtin_amdgcn_mfma_f32_16x16x32_bf16(ah[m],  bl_[n], acc[m][n], 0, 0, 0);
        acc[m][n] = __builtin_amdgcn_mfma_f32_16x16x32_bf16(al_[m], bh[n],  acc[m][n], 0, 0, 0);
      }
    // one barrier per step: built-in vmcnt(0)+lgkmcnt(0) drain lands AFTER
    // the MFMA phase, so prefetch latency is hidden under compute.
    __syncthreads();
    cur ^= 1;
  }

  // ---- fused alpha: s1[row] = sum_c h[row][c]*a_src[hd][c], s2 likewise ----
  const float* as_v = av_s + hd * HIDC;
  const float* ad_v = av_d + hd * HIDC;
#pragma unroll
  for (int m = 0; m < 4; ++m)
#pragma unroll
    for (int i = 0; i < 4; ++i) {
      float s1 = 0.f, s2 = 0.f;
#pragma unroll
      for (int n = 0; n < 4; ++n) {
        int c = wc * 64 + n * 16 + (l & 15);
        float v = acc[m][n][i];
        s1 += v * as_v[c];
        s2 += v * ad_v[c];
      }
#pragma unroll
      for (int off = 1; off < 16; off <<= 1) {
        s1 += __shfl_xor(s1, off);
        s2 += __shfl_xor(s2, off);
      }
      if ((l & 15) == 0) {
        int rl = wr * 64 + m * 16 + (l >> 4) * 4 + i;
        red1[rl][wc] = s1;
        red2[rl][wc] = s2;
      }
    }
  __syncthreads();
  if (tid < 128) {
    int row = row0 + tid;
    if (row < M) {
      asrcO[row * H + hd] = red1[tid][0] + red1[tid][1];
      adstO[row * H + hd] = red2[tid][0] + red2[tid][1];
    }
  }

  // ---- C write ----
#pragma unroll
  for (int m = 0; m < 4; ++m) {
#pragma unroll
    for (int i = 0; i < 4; ++i) {
      int row = row0 + wr * 64 + m * 16 + (l >> 4) * 4 + i;
      if (row < M) {
#pragma unroll
        for (int n = 0; n < 4; ++n) {
          int colg = col0 + wc * 64 + n * 16 + (l & 15);
          if (Ch) Ch[(size_t)row * N + colg] = __float2half(acc[m][n][i]);
          else    Cf[(size_t)row * N + colg] = acc[m][n][i];
        }
      }
    }
  }
}

// ================== GAT aggregation, fp16 gather (layers 1/2) ==================
// Phase A (lanes over edges): e -> wave-max -> p=exp(e-m) cached in LDS + sum.
// Phase B (lanes over channels): serial edge loop = LDS p + h16 gather + FMA.
__global__ __launch_bounds__(256) void k_aggregate16(
    const __half* __restrict__ h16,   // [N][512]
    const float* __restrict__ asrc, const float* __restrict__ adst,
    const int* __restrict__ row_ptr, const int* __restrict__ col,
    const float* __restrict__ bias,   // [512]
    short* __restrict__ oh, short* __restrict__ ol) {
  __shared__ float p_lds[NHEADS][DEGCAP];
  __shared__ int   s_lds[DEGCAP];

  int n = blockIdx.x;
  int w = threadIdx.x >> 6;
  int l = threadIdx.x & 63;
  int r0 = row_ptr[n], r1 = row_ptr[n + 1];
  int D = r1 - r0;
  float adn = adst[n * NHEADS + w];

  // ---- phase A: per-head max, then p into LDS + sum ----
  float m = -INFINITY;
  for (int jj = l; jj < D; jj += 64) {
    int s = col[r0 + jj];
    if (w == 0 && jj < DEGCAP) s_lds[jj] = s;
    float e = asrc[s * NHEADS + w] + adn;
    e = e > 0.f ? e : NEG_SLOPE * e;
    m = fmaxf(m, e);
    if (jj < DEGCAP) p_lds[w][jj] = e;   // stash raw e; exp after max known
  }
#pragma unroll
  for (int off = 32; off; off >>= 1) m = fmaxf(m, __shfl_xor(m, off));

  float ssum = 0.f;
  for (int jj = l; jj < D; jj += 64) {
    float e;
    if (jj < DEGCAP) e = p_lds[w][jj];
    else {
      int s = col[r0 + jj];
      e = asrc[s * NHEADS + w] + adn;
      e = e > 0.f ? e : NEG_SLOPE * e;
    }
    float p = __expf(e - m);
    ssum += p;
    if (jj < DEGCAP) p_lds[w][jj] = p;
  }
#pragma unroll
  for (int off = 32; off; off >>= 1) ssum += __shfl_xor(ssum, off);
  __syncthreads();  // publish p_lds / s_lds

  // ---- phase B: channel-parallel accumulation ----
  float acc0 = 0.f, acc1 = 0.f;
  int Dc = D < DEGCAP ? D : DEGCAP;
  for (int jj = 0; jj < Dc; ++jj) {
    float p = p_lds[w][jj];
    int s = s_lds[jj];
    __half2 hh = *((const __half2*)(h16 + (size_t)s * 512 + w * 128) + l);
    float2 hv = __half22float2(hh);
    acc0 += p * hv.x;
    acc1 += p * hv.y;
  }
  for (int jj = Dc; jj < D; ++jj) {  // rare overflow path
    int s = col[r0 + jj];
    float e = asrc[s * NHEADS + w] + adn;
    e = e > 0.f ? e : NEG_SLOPE * e;
    float p = __expf(e - m);
    __half2 hh = *((const __half2*)(h16 + (size_t)s * 512 + w * 128) + l);
    float2 hv = __half22float2(hh);
    acc0 += p * hv.x;
    acc1 += p * hv.y;
  }

  float inv = 1.f / (ssum + 1e-16f);
  int c0 = w * 128 + 2 * l;
  float o0 = acc0 * inv + bias[c0];
  float o1 = acc1 * inv + bias[c0 + 1];
  o0 = o0 > 0.f ? o0 : (__expf(o0) - 1.f);  // ELU
  o1 = o1 > 0.f ? o1 : (__expf(o1) - 1.f);

  size_t i0 = (size_t)n * 512 + c0;
  unsigned short h0 = bf16hi(o0);
  unsigned short h1 = bf16hi(o1);
  float f0 = __uint_as_float((unsigned)h0 << 16);
  float f1 = __uint_as_float((unsigned)h1 << 16);
  unsigned short l0 = bf16hi(o0 - f0);
  unsigned short l1 = bf16hi(o1 - f1);
  *(unsigned*)(oh + i0) = (unsigned)h0 | ((unsigned)h1 << 16);
  *(unsigned*)(ol + i0) = (unsigned)l0 | ((unsigned)l1 << 16);
}

// ============== GAT aggregation, fp32 (layer 3, final output) ==============
__global__ void k_aggregate(const float* __restrict__ h,     // [N][128]
                            const float* __restrict__ asrc,
                            const float* __restrict__ adst,
                            const int* __restrict__ row_ptr,
                            const int* __restrict__ col,
                            const float* __restrict__ bias,
                            float* __restrict__ outf) {
  const int C = HIDC;
  int n = blockIdx.x;
  int l = threadIdx.x & 63;
  int r0 = row_ptr[n], r1 = row_ptr[n + 1];
  float adn = adst[n];

  float m = -INFINITY;
  for (int j = r0 + l; j < r1; j += 64) {
    int s = col[j];
    float e = asrc[s] + adn;
    e = e > 0.f ? e : NEG_SLOPE * e;
    m = fmaxf(m, e);
  }
#pragma unroll
  for (int off = 32; off; off >>= 1) m = fmaxf(m, __shfl_xor(m, off));

  float acc0 = 0.f, acc1 = 0.f, ssum = 0.f;
  for (int j = r0; j < r1; ++j) {
    int s = col[j];
    float e = asrc[s] + adn;
    e = e > 0.f ? e : NEG_SLOPE * e;
    float p = __expf(e - m);
    ssum += p;
    const float* hr = h + (size_t)s * C;
    acc0 += p * hr[l];
    acc1 += p * hr[l + 64];
  }
  float inv = 1.f / (ssum + 1e-16f);
  outf[(size_t)n * C + l]      = acc0 * inv + bias[l];
  outf[(size_t)n * C + l + 64] = acc1 * inv + bias[l + 64];
}

// ============================ launcher ============================

extern "C" void kernel_launch(void* const* d_in, const int* in_sizes, int n_in,
                              void* d_out, int out_size, void* d_ws, size_t ws_size,
                              hipStream_t stream) {
  const float* x      = (const float*)d_in[0];
  const int*   ei     = (const int*)d_in[1];
  const float* W1     = (const float*)d_in[2];
  const float* a1_src = (const float*)d_in[3];
  const float* a1_dst = (const float*)d_in[4];
  const float* b1     = (const float*)d_in[5];
  const float* W2     = (const float*)d_in[6];
  const float* a2_src = (const float*)d_in[7];
  const float* a2_dst = (const float*)d_in[8];
  const float* b2     = (const float*)d_in[9];
  const float* W3     = (const float*)d_in[10];
  const float* a3_src = (const float*)d_in[11];
  const float* a3_dst = (const float*)d_in[12];
  const float* b3     = (const float*)d_in[13];
  float* out = (float*)d_out;

  char* ws = (char*)d_ws;
  size_t off = 0;
  auto alloc = [&](size_t bytes) {
    size_t r = off;
    off = (off + bytes + 255) & ~(size_t)255;
    return r;
  };
  short* Aih = (short*)(ws + alloc((size_t)MPAD * INC * 2));
  short* Ail = (short*)(ws + alloc((size_t)MPAD * INC * 2));
  short* w1h = (short*)(ws + alloc((size_t)512 * INC * 2));
  short* w1l = (short*)(ws + alloc((size_t)512 * INC * 2));
  short* w2h = (short*)(ws + alloc((size_t)512 * 512 * 2));
  short* w2l = (short*)(ws + alloc((size_t)512 * 512 * 2));
  short* w3h = (short*)(ws + alloc((size_t)128 * 512 * 2));
  short* w3l = (short*)(ws + alloc((size_t)128 * 512 * 2));
  __half* h16    = (__half*)(ws + alloc((size_t)MPAD * 512 * 2));
  float* hA      = (float*)(ws + alloc((size_t)NNODES * HIDC * 4));
  float* asrc    = (float*)(ws + alloc((size_t)NNODES * NHEADS * 4));
  float* adst    = (float*)(ws + alloc((size_t)NNODES * NHEADS * 4));
  int*   row_ptr = (int*)(ws + alloc((size_t)(NNODES + 1) * 4));
  int*   fill    = (int*)(ws + alloc((size_t)NNODES * 4));
  int*   cnt     = (int*)(ws + alloc((size_t)NNODES * 4));
  int*   colv    = (int*)(ws + alloc((size_t)(NEDGES + NNODES) * 4));

  const int TOT = NEDGES + NNODES;

  // ---- CSR build ----
  k_zero<<<(NNODES + 255) / 256, 256, 0, stream>>>(cnt, NNODES);
  k_count<<<(TOT + 255) / 256, 256, 0, stream>>>(ei, cnt);
  k_scan<<<1, 1024, 0, stream>>>(cnt, row_ptr, fill);
  k_fill<<<(TOT + 255) / 256, 256, 0, stream>>>(ei, fill, colv);

  // ---- decompose inputs & weights ----
  k_decomp<<<(NNODES * INC + 255) / 256, 256, 0, stream>>>(x, Aih, Ail, NNODES * INC);
  k_decomp_wt<<<dim3(512 / 32, INC / 32), 256, 0, stream>>>(W1, w1h, w1l, INC, 512);
  k_decomp_wt<<<dim3(512 / 32, 512 / 32), 256, 0, stream>>>(W2, w2h, w2l, 512, 512);
  k_decomp_wt<<<dim3(128 / 32, 512 / 32), 256, 0, stream>>>(W3, w3h, w3l, 512, 128);

  const int GY = MPAD / 128;  // 157

  // ---- layer 1 ----
  k_gemm_bf16<<<dim3(512 / 128, GY), 256, 0, stream>>>(
      Aih, Ail, w1h, w1l, nullptr, h16, a1_src, a1_dst, asrc, adst,
      NNODES, 512, INC, NHEADS);
  k_aggregate16<<<NNODES, 256, 0, stream>>>(h16, asrc, adst, row_ptr, colv,
                                            b1, Aih, Ail);

  // ---- layer 2 ----
  k_gemm_bf16<<<dim3(512 / 128, GY), 256, 0, stream>>>(
      Aih, Ail, w2h, w2l, nullptr, h16, a2_src, a2_dst, asrc, adst,
      NNODES, 512, 512, NHEADS);
  k_aggregate16<<<NNODES, 256, 0, stream>>>(h16, asrc, adst, row_ptr, colv,
                                            b2, Aih, Ail);

  // ---- layer 3 ----
  k_gemm_bf16<<<dim3(1, GY), 256, 0, stream>>>(
      Aih, Ail, w3h, w3l, hA, nullptr, a3_src, a3_dst, asrc, adst,
      NNODES, 128, 512, 1);
  k_aggregate<<<NNODES, 64, 0, stream>>>(hA, asrc, adst, row_ptr, colv, b3, out);
}

// Round 9
// 527.976 us; speedup vs baseline: 1.7261x; 1.0062x over previous
//
#include <hip/hip_runtime.h>
#include <hip/hip_fp16.h>
#include <math.h>

#define NNODES 20000
#define MPAD   20096   // NNODES rounded up to 128
#define NEDGES 400000
#define INC    768
#define HIDC   128
#define NHEADS 4
#define NEG_SLOPE 0.2f
#define DEGCAP 512     // per-head LDS cache of edge weights

typedef __attribute__((ext_vector_type(8))) short bf16x8;
typedef __attribute__((ext_vector_type(4))) float f32x4;

// round-to-nearest-even fp32 -> bf16 (bits)
__device__ __forceinline__ unsigned short bf16hi(float v) {
  unsigned u = __float_as_uint(v);
  return (unsigned short)((u + 0x7fffu + ((u >> 16) & 1u)) >> 16);
}

__device__ __forceinline__ void gload16(const void* g, void* l) {
  __builtin_amdgcn_global_load_lds(
      (const __attribute__((address_space(1))) unsigned int*)g,
      (__attribute__((address_space(3))) unsigned int*)l, 16, 0, 0);
}

// ============================ CSR build ============================

__global__ void k_zero(int* __restrict__ p, int n) {
  int i = blockIdx.x * blockDim.x + threadIdx.x;
  if (i < n) p[i] = 0;
}

__global__ void k_count(const int* __restrict__ ei, int* __restrict__ cnt) {
  int i = blockIdx.x * blockDim.x + threadIdx.x;
  const int tot = NEDGES + NNODES;
  if (i >= tot) return;
  int dst = (i < NEDGES) ? ei[NEDGES + i] : (i - NEDGES);
  atomicAdd(&cnt[dst], 1);
}

__global__ void k_scan(const int* __restrict__ cnt, int* __restrict__ row_ptr,
                       int* __restrict__ fill) {
  __shared__ int part[1024];
  int t = threadIdx.x;
  const int chunk = (NNODES + 1023) / 1024;
  int lo = t * chunk, hi = min(lo + chunk, NNODES);
  int s = 0;
  for (int i = lo; i < hi; ++i) s += cnt[i];
  part[t] = s;
  __syncthreads();
  for (int off = 1; off < 1024; off <<= 1) {
    int v = (t >= off) ? part[t - off] : 0;
    __syncthreads();
    part[t] += v;
    __syncthreads();
  }
  int pref = (t == 0) ? 0 : part[t - 1];
  for (int i = lo; i < hi; ++i) {
    row_ptr[i] = pref;
    fill[i] = pref;
    pref += cnt[i];
  }
  if (t == 1023) row_ptr[NNODES] = part[1023];
}

__global__ void k_fill(const int* __restrict__ ei, int* __restrict__ fill,
                       int* __restrict__ col) {
  int i = blockIdx.x * blockDim.x + threadIdx.x;
  const int tot = NEDGES + NNODES;
  if (i >= tot) return;
  int srcv, dstv;
  if (i < NEDGES) { srcv = ei[i]; dstv = ei[NEDGES + i]; }
  else            { srcv = i - NEDGES; dstv = srcv; }
  int pos = atomicAdd(&fill[dstv], 1);
  col[pos] = srcv;
}

// ========================= decompose kernels =========================

__global__ void k_decomp(const float* __restrict__ in, short* __restrict__ hi,
                         short* __restrict__ lo, int n) {
  int i = blockIdx.x * blockDim.x + threadIdx.x;
  if (i >= n) return;
  float v = in[i];
  unsigned short h = bf16hi(v);
  float hf = __uint_as_float((unsigned)h << 16);
  hi[i] = (short)h;
  lo[i] = (short)bf16hi(v - hf);
}

// W [K][N] fp32 -> W^T hi/lo [N][K] bf16 (LDS-tiled transpose)
__global__ __launch_bounds__(256) void k_decomp_wt(
    const float* __restrict__ W, short* __restrict__ th, short* __restrict__ tl,
    int K, int N) {
  __shared__ float t[32][33];
  int bn = blockIdx.x, bk = blockIdx.y;
  int tx = threadIdx.x & 31, ty = threadIdx.x >> 5;  // 32 x 8
#pragma unroll
  for (int r = 0; r < 4; ++r)
    t[ty + r * 8][tx] = W[(size_t)(bk * 32 + ty + r * 8) * N + bn * 32 + tx];
  __syncthreads();
#pragma unroll
  for (int r = 0; r < 4; ++r) {
    int n = bn * 32 + ty + r * 8;
    int k = bk * 32 + tx;
    float v = t[tx][ty + r * 8];
    unsigned short h = bf16hi(v);
    float hf = __uint_as_float((unsigned)h << 16);
    th[(size_t)n * K + k] = (short)h;
    tl[(size_t)n * K + k] = (short)bf16hi(v - hf);
  }
}

// ==================== split-bf16 MFMA GEMM + fused alpha ====================
// LDS tiles fused h|l: [128 rows][8 x 16B chunks], bank-conflict-free via
// involution swizzle phys_chunk = logical_chunk ^ (row&7); staged with linear
// gload_lds dest + inverse-swizzled per-lane global source (rule 21).
// 2-phase double-buffer + bijective chunked XCD swizzle.
__global__ __launch_bounds__(256) void k_gemm_bf16(
    const short* __restrict__ Ah, const short* __restrict__ Al,
    const short* __restrict__ Bth, const short* __restrict__ Btl,
    float* __restrict__ Cf, __half* __restrict__ Ch,
    const float* __restrict__ av_s, const float* __restrict__ av_d,
    float* __restrict__ asrcO, float* __restrict__ adstO,
    int M, int N, int K, int H) {
  __shared__ __align__(16) short As[2][128 * 64];
  __shared__ __align__(16) short Bs[2][128 * 64];
  __shared__ float red1[128][2];
  __shared__ float red2[128][2];

  const int tid = threadIdx.x;
  const int w = tid >> 6;
  const int l = tid & 63;
  const int wr = w >> 1, wc = w & 1;

  // ---- bijective chunked XCD swizzle: hw id -> logical tile ----
  const int nwg = gridDim.x * gridDim.y;
  const int h_id = blockIdx.y * gridDim.x + blockIdx.x;
  const int q = nwg >> 3, r8 = nwg & 7;
  const int xcd = h_id & 7, slot = h_id >> 3;
  const int logical = xcd * q + min(xcd, r8) + slot;
  const int by = logical / gridDim.x;
  const int bx = logical - by * gridDim.x;

  const int row0 = by * 128;
  const int col0 = bx * 128;
  const int hd = bx;  // 128 cols per head

  // ---- staging lane constants (8 rows x 128B per gload16) ----
  const int rsub  = l >> 3;        // row within 8-row slab
  const int cphys = l & 7;         // physical 16B chunk this lane fills
  const int clog  = cphys ^ rsub;  // logical chunk to fetch (involution)
  const int hiSel = clog < 4;
  const int csrc  = hiSel ? clog : clog - 4;   // chunk within 64B source row

  f32x4 acc[4][4];
#pragma unroll
  for (int i = 0; i < 4; ++i)
#pragma unroll
    for (int j = 0; j < 4; ++j) acc[i][j] = (f32x4){0.f, 0.f, 0.f, 0.f};

  const int fr = l & 15;   // frag row/col within 16
  const int ch = l >> 4;   // logical k-chunk of the frag (0..3)

  auto stage = [&](int buf, int k0) {
#pragma unroll
    for (int qq = 0; qq < 2; ++qq) {
#pragma unroll
      for (int sub = 0; sub < 2; ++sub) {
        int R = qq * 64 + w * 16 + sub * 8;   // wave-uniform slab base row
        int gA = row0 + R + rsub;
        const short* srcA = (hiSel ? Ah : Al) + (size_t)gA * K + k0 + csrc * 8;
        gload16(srcA, &As[buf][R * 64]);
        int gB = col0 + R + rsub;
        const short* srcB = (hiSel ? Bth : Btl) + (size_t)gB * K + k0 + csrc * 8;
        gload16(srcB, &Bs[buf][R * 64]);
      }
    }
  };

  // prologue: stage first tile, drain
  stage(0, 0);
  __syncthreads();

  int cur = 0;
  for (int k0 = 0; k0 < K; k0 += 32) {
    // prefetch next K-tile into the other buffer (flies during MFMA below)
    if (k0 + 32 < K) stage(cur ^ 1, k0 + 32);

    bf16x8 ah[4], al_[4], bh[4], bl_[4];
#pragma unroll
    for (int m = 0; m < 4; ++m) {
      int ar = wr * 64 + m * 16 + fr;
      int pa = (ch ^ (ar & 7)) * 8;               // swizzled chunk (shorts)
      ah[m]  = *(const bf16x8*)&As[cur][ar * 64 + pa];
      al_[m] = *(const bf16x8*)&As[cur][ar * 64 + (pa ^ 32)];  // l-half: chunk^4
      int bc = wc * 64 + m * 16 + fr;
      int pb = (ch ^ (bc & 7)) * 8;
      bh[m]  = *(const bf16x8*)&Bs[cur][bc * 64 + pb];
      bl_[m] = *(const bf16x8*)&Bs[cur][bc * 64 + (pb ^ 32)];
    }
#pragma unroll
    for (int m = 0; m < 4; ++m)
#pragma unroll
      for (int n = 0; n < 4; ++n) {
        acc[m][n] = __builtin_amdgcn_mfma_f32_16x16x32_bf16(ah[m],  bh[n],  acc[m][n], 0, 0, 0);
        acc[m][n] = __builtin_amdgcn_mfma_f32_16x16x32_bf16(ah[m],  bl_[n], acc[m][n], 0, 0, 0);
        acc[m][n] = __builtin_amdgcn_mfma_f32_16x16x32_bf16(al_[m], bh[n],  acc[m][n], 0, 0, 0);
      }
    // one barrier per step: built-in vmcnt(0)+lgkmcnt(0) drain lands AFTER
    // the MFMA phase, so prefetch latency is hidden under compute.
    __syncthreads();
    cur ^= 1;
  }

  // ---- fused alpha: s1[row] = sum_c h[row][c]*a_src[hd][c], s2 likewise ----
  const float* as_v = av_s + hd * HIDC;
  const float* ad_v = av_d + hd * HIDC;
#pragma unroll
  for (int m = 0; m < 4; ++m)
#pragma unroll
    for (int i = 0; i < 4; ++i) {
      float s1 = 0.f, s2 = 0.f;
#pragma unroll
      for (int n = 0; n < 4; ++n) {
        int c = wc * 64 + n * 16 + (l & 15);
        float v = acc[m][n][i];
        s1 += v * as_v[c];
        s2 += v * ad_v[c];
      }
#pragma unroll
      for (int off = 1; off < 16; off <<= 1) {
        s1 += __shfl_xor(s1, off);
        s2 += __shfl_xor(s2, off);
      }
      if ((l & 15) == 0) {
        int rl = wr * 64 + m * 16 + (l >> 4) * 4 + i;
        red1[rl][wc] = s1;
        red2[rl][wc] = s2;
      }
    }
  __syncthreads();
  if (tid < 128) {
    int row = row0 + tid;
    if (row < M) {
      asrcO[row * H + hd] = red1[tid][0] + red1[tid][1];
      adstO[row * H + hd] = red2[tid][0] + red2[tid][1];
    }
  }

  // ---- C write ----
#pragma unroll
  for (int m = 0; m < 4; ++m) {
#pragma unroll
    for (int i = 0; i < 4; ++i) {
      int row = row0 + wr * 64 + m * 16 + (l >> 4) * 4 + i;
      if (row < M) {
#pragma unroll
        for (int n = 0; n < 4; ++n) {
          int colg = col0 + wc * 64 + n * 16 + (l & 15);
          if (Ch) Ch[(size_t)row * N + colg] = __float2half(acc[m][n][i]);
          else    Cf[(size_t)row * N + colg] = acc[m][n][i];
        }
      }
    }
  }
}

// ================== GAT aggregation, fp16 gather (layers 1/2) ==================
// Phase A (lanes over edges): e -> wave-max -> p=exp(e-m) cached in LDS + sum.
// Phase B (lanes over channels): serial edge loop = LDS p + h16 gather + FMA.
__global__ __launch_bounds__(256) void k_aggregate16(
    const __half* __restrict__ h16,   // [N][512]
    const float* __restrict__ asrc, const float* __restrict__ adst,
    const int* __restrict__ row_ptr, const int* __restrict__ col,
    const float* __restrict__ bias,   // [512]
    short* __restrict__ oh, short* __restrict__ ol) {
  __shared__ float p_lds[NHEADS][DEGCAP];
  __shared__ int   s_lds[DEGCAP];

  int n = blockIdx.x;
  int w = threadIdx.x >> 6;
  int l = threadIdx.x & 63;
  int r0 = row_ptr[n], r1 = row_ptr[n + 1];
  int D = r1 - r0;
  float adn = adst[n * NHEADS + w];

  // ---- phase A: per-head max, then p into LDS + sum ----
  float m = -INFINITY;
  for (int jj = l; jj < D; jj += 64) {
    int s = col[r0 + jj];
    if (w == 0 && jj < DEGCAP) s_lds[jj] = s;
    float e = asrc[s * NHEADS + w] + adn;
    e = e > 0.f ? e : NEG_SLOPE * e;
    m = fmaxf(m, e);
    if (jj < DEGCAP) p_lds[w][jj] = e;   // stash raw e; exp after max known
  }
#pragma unroll
  for (int off = 32; off; off >>= 1) m = fmaxf(m, __shfl_xor(m, off));

  float ssum = 0.f;
  for (int jj = l; jj < D; jj += 64) {
    float e;
    if (jj < DEGCAP) e = p_lds[w][jj];
    else {
      int s = col[r0 + jj];
      e = asrc[s * NHEADS + w] + adn;
      e = e > 0.f ? e : NEG_SLOPE * e;
    }
    float p = __expf(e - m);
    ssum += p;
    if (jj < DEGCAP) p_lds[w][jj] = p;
  }
#pragma unroll
  for (int off = 32; off; off >>= 1) ssum += __shfl_xor(ssum, off);
  __syncthreads();  // publish p_lds / s_lds

  // ---- phase B: channel-parallel accumulation ----
  float acc0 = 0.f, acc1 = 0.f;
  int Dc = D < DEGCAP ? D : DEGCAP;
  for (int jj = 0; jj < Dc; ++jj) {
    float p = p_lds[w][jj];
    int s = s_lds[jj];
    __half2 hh = *((const __half2*)(h16 + (size_t)s * 512 + w * 128) + l);
    float2 hv = __half22float2(hh);
    acc0 += p * hv.x;
    acc1 += p * hv.y;
  }
  for (int jj = Dc; jj < D; ++jj) {  // rare overflow path
    int s = col[r0 + jj];
    float e = asrc[s * NHEADS + w] + adn;
    e = e > 0.f ? e : NEG_SLOPE * e;
    float p = __expf(e - m);
    __half2 hh = *((const __half2*)(h16 + (size_t)s * 512 + w * 128) + l);
    float2 hv = __half22float2(hh);
    acc0 += p * hv.x;
    acc1 += p * hv.y;
  }

  float inv = 1.f / (ssum + 1e-16f);
  int c0 = w * 128 + 2 * l;
  float o0 = acc0 * inv + bias[c0];
  float o1 = acc1 * inv + bias[c0 + 1];
  o0 = o0 > 0.f ? o0 : (__expf(o0) - 1.f);  // ELU
  o1 = o1 > 0.f ? o1 : (__expf(o1) - 1.f);

  size_t i0 = (size_t)n * 512 + c0;
  unsigned short h0 = bf16hi(o0);
  unsigned short h1 = bf16hi(o1);
  float f0 = __uint_as_float((unsigned)h0 << 16);
  float f1 = __uint_as_float((unsigned)h1 << 16);
  unsigned short l0 = bf16hi(o0 - f0);
  unsigned short l1 = bf16hi(o1 - f1);
  *(unsigned*)(oh + i0) = (unsigned)h0 | ((unsigned)h1 << 16);
  *(unsigned*)(ol + i0) = (unsigned)l0 | ((unsigned)l1 << 16);
}

// ============== GAT aggregation, fp32 (layer 3, final output) ==============
__global__ void k_aggregate(const float* __restrict__ h,     // [N][128]
                            const float* __restrict__ asrc,
                            const float* __restrict__ adst,
                            const int* __restrict__ row_ptr,
                            const int* __restrict__ col,
                            const float* __restrict__ bias,
                            float* __restrict__ outf) {
  const int C = HIDC;
  int n = blockIdx.x;
  int l = threadIdx.x & 63;
  int r0 = row_ptr[n], r1 = row_ptr[n + 1];
  float adn = adst[n];

  float m = -INFINITY;
  for (int j = r0 + l; j < r1; j += 64) {
    int s = col[j];
    float e = asrc[s] + adn;
    e = e > 0.f ? e : NEG_SLOPE * e;
    m = fmaxf(m, e);
  }
#pragma unroll
  for (int off = 32; off; off >>= 1) m = fmaxf(m, __shfl_xor(m, off));

  float acc0 = 0.f, acc1 = 0.f, ssum = 0.f;
  for (int j = r0; j < r1; ++j) {
    int s = col[j];
    float e = asrc[s] + adn;
    e = e > 0.f ? e : NEG_SLOPE * e;
    float p = __expf(e - m);
    ssum += p;
    const float* hr = h + (size_t)s * C;
    acc0 += p * hr[l];
    acc1 += p * hr[l + 64];
  }
  float inv = 1.f / (ssum + 1e-16f);
  outf[(size_t)n * C + l]      = acc0 * inv + bias[l];
  outf[(size_t)n * C + l + 64] = acc1 * inv + bias[l + 64];
}

// ============================ launcher ============================

extern "C" void kernel_launch(void* const* d_in, const int* in_sizes, int n_in,
                              void* d_out, int out_size, void* d_ws, size_t ws_size,
                              hipStream_t stream) {
  const float* x      = (const float*)d_in[0];
  const int*   ei     = (const int*)d_in[1];
  const float* W1     = (const float*)d_in[2];
  const float* a1_src = (const float*)d_in[3];
  const float* a1_dst = (const float*)d_in[4];
  const float* b1     = (const float*)d_in[5];
  const float* W2     = (const float*)d_in[6];
  const float* a2_src = (const float*)d_in[7];
  const float* a2_dst = (const float*)d_in[8];
  const float* b2     = (const float*)d_in[9];
  const float* W3     = (const float*)d_in[10];
  const float* a3_src = (const float*)d_in[11];
  const float* a3_dst = (const float*)d_in[12];
  const float* b3     = (const float*)d_in[13];
  float* out = (float*)d_out;

  char* ws = (char*)d_ws;
  size_t off = 0;
  auto alloc = [&](size_t bytes) {
    size_t r = off;
    off = (off + bytes + 255) & ~(size_t)255;
    return r;
  };
  short* Aih = (short*)(ws + alloc((size_t)MPAD * INC * 2));
  short* Ail = (short*)(ws + alloc((size_t)MPAD * INC * 2));
  short* w1h = (short*)(ws + alloc((size_t)512 * INC * 2));
  short* w1l = (short*)(ws + alloc((size_t)512 * INC * 2));
  short* w2h = (short*)(ws + alloc((size_t)512 * 512 * 2));
  short* w2l = (short*)(ws + alloc((size_t)512 * 512 * 2));
  short* w3h = (short*)(ws + alloc((size_t)128 * 512 * 2));
  short* w3l = (short*)(ws + alloc((size_t)128 * 512 * 2));
  __half* h16    = (__half*)(ws + alloc((size_t)MPAD * 512 * 2));
  float* hA      = (float*)(ws + alloc((size_t)NNODES * HIDC * 4));
  float* asrc    = (float*)(ws + alloc((size_t)NNODES * NHEADS * 4));
  float* adst    = (float*)(ws + alloc((size_t)NNODES * NHEADS * 4));
  int*   row_ptr = (int*)(ws + alloc((size_t)(NNODES + 1) * 4));
  int*   fill    = (int*)(ws + alloc((size_t)NNODES * 4));
  int*   cnt     = (int*)(ws + alloc((size_t)NNODES * 4));
  int*   colv    = (int*)(ws + alloc((size_t)(NEDGES + NNODES) * 4));

  const int TOT = NEDGES + NNODES;

  // ---- CSR build ----
  k_zero<<<(NNODES + 255) / 256, 256, 0, stream>>>(cnt, NNODES);
  k_count<<<(TOT + 255) / 256, 256, 0, stream>>>(ei, cnt);
  k_scan<<<1, 1024, 0, stream>>>(cnt, row_ptr, fill);
  k_fill<<<(TOT + 255) / 256, 256, 0, stream>>>(ei, fill, colv);

  // ---- decompose inputs & weights ----
  k_decomp<<<(NNODES * INC + 255) / 256, 256, 0, stream>>>(x, Aih, Ail, NNODES * INC);
  k_decomp_wt<<<dim3(512 / 32, INC / 32), 256, 0, stream>>>(W1, w1h, w1l, INC, 512);
  k_decomp_wt<<<dim3(512 / 32, 512 / 32), 256, 0, stream>>>(W2, w2h, w2l, 512, 512);
  k_decomp_wt<<<dim3(128 / 32, 512 / 32), 256, 0, stream>>>(W3, w3h, w3l, 512, 128);

  const int GY = MPAD / 128;  // 157

  // ---- layer 1 ----
  k_gemm_bf16<<<dim3(512 / 128, GY), 256, 0, stream>>>(
      Aih, Ail, w1h, w1l, nullptr, h16, a1_src, a1_dst, asrc, adst,
      NNODES, 512, INC, NHEADS);
  k_aggregate16<<<NNODES, 256, 0, stream>>>(h16, asrc, adst, row_ptr, colv,
                                            b1, Aih, Ail);

  // ---- layer 2 ----
  k_gemm_bf16<<<dim3(512 / 128, GY), 256, 0, stream>>>(
      Aih, Ail, w2h, w2l, nullptr, h16, a2_src, a2_dst, asrc, adst,
      NNODES, 512, 512, NHEADS);
  k_aggregate16<<<NNODES, 256, 0, stream>>>(h16, asrc, adst, row_ptr, colv,
                                            b2, Aih, Ail);

  // ---- layer 3 ----
  k_gemm_bf16<<<dim3(1, GY), 256, 0, stream>>>(
      Aih, Ail, w3h, w3l, hA, nullptr, a3_src, a3_dst, asrc, adst,
      NNODES, 128, 512, 1);
  k_aggregate<<<NNODES, 64, 0, stream>>>(hA, asrc, adst, row_ptr, colv, b3, out);
}

// Round 10
// 517.851 us; speedup vs baseline: 1.7598x; 1.0196x over previous
//
#include <hip/hip_runtime.h>
#include <hip/hip_fp16.h>
#include <math.h>

#define NNODES 20000
#define MPAD   20096   // NNODES rounded up to 128
#define NEDGES 400000
#define INC    768
#define HIDC   128
#define NHEADS 4
#define NEG_SLOPE 0.2f
#define DEGCAP 512     // per-head LDS cache of edge weights

typedef __attribute__((ext_vector_type(8))) short bf16x8;
typedef __attribute__((ext_vector_type(4))) float f32x4;

// round-to-nearest-even fp32 -> bf16 (bits)
__device__ __forceinline__ unsigned short bf16hi(float v) {
  unsigned u = __float_as_uint(v);
  return (unsigned short)((u + 0x7fffu + ((u >> 16) & 1u)) >> 16);
}

__device__ __forceinline__ void gload16(const void* g, void* l) {
  __builtin_amdgcn_global_load_lds(
      (const __attribute__((address_space(1))) unsigned int*)g,
      (__attribute__((address_space(3))) unsigned int*)l, 16, 0, 0);
}

// ============================ CSR build ============================

__global__ void k_zero(int* __restrict__ p, int n) {
  int i = blockIdx.x * blockDim.x + threadIdx.x;
  if (i < n) p[i] = 0;
}

__global__ void k_count(const int* __restrict__ ei, int* __restrict__ cnt) {
  int i = blockIdx.x * blockDim.x + threadIdx.x;
  const int tot = NEDGES + NNODES;
  if (i >= tot) return;
  int dst = (i < NEDGES) ? ei[NEDGES + i] : (i - NEDGES);
  atomicAdd(&cnt[dst], 1);
}

__global__ void k_scan(const int* __restrict__ cnt, int* __restrict__ row_ptr,
                       int* __restrict__ fill) {
  __shared__ int part[1024];
  int t = threadIdx.x;
  const int chunk = (NNODES + 1023) / 1024;
  int lo = t * chunk, hi = min(lo + chunk, NNODES);
  int s = 0;
  for (int i = lo; i < hi; ++i) s += cnt[i];
  part[t] = s;
  __syncthreads();
  for (int off = 1; off < 1024; off <<= 1) {
    int v = (t >= off) ? part[t - off] : 0;
    __syncthreads();
    part[t] += v;
    __syncthreads();
  }
  int pref = (t == 0) ? 0 : part[t - 1];
  for (int i = lo; i < hi; ++i) {
    row_ptr[i] = pref;
    fill[i] = pref;
    pref += cnt[i];
  }
  if (t == 1023) row_ptr[NNODES] = part[1023];
}

__global__ void k_fill(const int* __restrict__ ei, int* __restrict__ fill,
                       int* __restrict__ col) {
  int i = blockIdx.x * blockDim.x + threadIdx.x;
  const int tot = NEDGES + NNODES;
  if (i >= tot) return;
  int srcv, dstv;
  if (i < NEDGES) { srcv = ei[i]; dstv = ei[NEDGES + i]; }
  else            { srcv = i - NEDGES; dstv = srcv; }
  int pos = atomicAdd(&fill[dstv], 1);
  col[pos] = srcv;
}

// ========================= decompose kernels =========================

__global__ void k_decomp(const float* __restrict__ in, short* __restrict__ hi,
                         short* __restrict__ lo, int n) {
  int i = blockIdx.x * blockDim.x + threadIdx.x;
  if (i >= n) return;
  float v = in[i];
  unsigned short h = bf16hi(v);
  float hf = __uint_as_float((unsigned)h << 16);
  hi[i] = (short)h;
  lo[i] = (short)bf16hi(v - hf);
}

// W [K][N] fp32 -> W^T hi/lo [N][K] bf16 (LDS-tiled transpose)
__global__ __launch_bounds__(256) void k_decomp_wt(
    const float* __restrict__ W, short* __restrict__ th, short* __restrict__ tl,
    int K, int N) {
  __shared__ float t[32][33];
  int bn = blockIdx.x, bk = blockIdx.y;
  int tx = threadIdx.x & 31, ty = threadIdx.x >> 5;  // 32 x 8
#pragma unroll
  for (int r = 0; r < 4; ++r)
    t[ty + r * 8][tx] = W[(size_t)(bk * 32 + ty + r * 8) * N + bn * 32 + tx];
  __syncthreads();
#pragma unroll
  for (int r = 0; r < 4; ++r) {
    int n = bn * 32 + ty + r * 8;
    int k = bk * 32 + tx;
    float v = t[tx][ty + r * 8];
    unsigned short h = bf16hi(v);
    float hf = __uint_as_float((unsigned)h << 16);
    th[(size_t)n * K + k] = (short)h;
    tl[(size_t)n * K + k] = (short)bf16hi(v - hf);
  }
}

// ==================== split-bf16 MFMA GEMM + fused alpha ====================
// LDS tiles fused h|l: [128 rows][8 x 16B chunks], bank-conflict-free via
// involution swizzle phys_chunk = logical_chunk ^ (row&7); staged with linear
// gload_lds dest + inverse-swizzled per-lane global source (rule 21).
// 2-phase double-buffer + bijective chunked XCD swizzle.
__global__ __launch_bounds__(256) void k_gemm_bf16(
    const short* __restrict__ Ah, const short* __restrict__ Al,
    const short* __restrict__ Bth, const short* __restrict__ Btl,
    float* __restrict__ Cf, __half* __restrict__ Ch,
    const float* __restrict__ av_s, const float* __restrict__ av_d,
    float* __restrict__ asrcO, float* __restrict__ adstO,
    int M, int N, int K, int H) {
  __shared__ __align__(16) short As[2][128 * 64];
  __shared__ __align__(16) short Bs[2][128 * 64];
  __shared__ float red1[128][2];
  __shared__ float red2[128][2];

  const int tid = threadIdx.x;
  const int w = tid >> 6;
  const int l = tid & 63;
  const int wr = w >> 1, wc = w & 1;

  // ---- bijective chunked XCD swizzle: hw id -> logical tile ----
  const int nwg = gridDim.x * gridDim.y;
  const int h_id = blockIdx.y * gridDim.x + blockIdx.x;
  const int q = nwg >> 3, r8 = nwg & 7;
  const int xcd = h_id & 7, slot = h_id >> 3;
  const int logical = xcd * q + min(xcd, r8) + slot;
  const int by = logical / gridDim.x;
  const int bx = logical - by * gridDim.x;

  const int row0 = by * 128;
  const int col0 = bx * 128;
  const int hd = bx;  // 128 cols per head

  // ---- staging lane constants (8 rows x 128B per gload16) ----
  const int rsub  = l >> 3;        // row within 8-row slab
  const int cphys = l & 7;         // physical 16B chunk this lane fills
  const int clog  = cphys ^ rsub;  // logical chunk to fetch (involution)
  const int hiSel = clog < 4;
  const int csrc  = hiSel ? clog : clog - 4;   // chunk within 64B source row

  f32x4 acc[4][4];
#pragma unroll
  for (int i = 0; i < 4; ++i)
#pragma unroll
    for (int j = 0; j < 4; ++j) acc[i][j] = (f32x4){0.f, 0.f, 0.f, 0.f};

  const int fr = l & 15;   // frag row/col within 16
  const int ch = l >> 4;   // logical k-chunk of the frag (0..3)

  auto stage = [&](int buf, int k0) {
#pragma unroll
    for (int qq = 0; qq < 2; ++qq) {
#pragma unroll
      for (int sub = 0; sub < 2; ++sub) {
        int R = qq * 64 + w * 16 + sub * 8;   // wave-uniform slab base row
        int gA = row0 + R + rsub;
        const short* srcA = (hiSel ? Ah : Al) + (size_t)gA * K + k0 + csrc * 8;
        gload16(srcA, &As[buf][R * 64]);
        int gB = col0 + R + rsub;
        const short* srcB = (hiSel ? Bth : Btl) + (size_t)gB * K + k0 + csrc * 8;
        gload16(srcB, &Bs[buf][R * 64]);
      }
    }
  };

  // prologue: stage first tile, drain
  stage(0, 0);
  __syncthreads();

  int cur = 0;
  for (int k0 = 0; k0 < K; k0 += 32) {
    // prefetch next K-tile into the other buffer (flies during MFMA below)
    if (k0 + 32 < K) stage(cur ^ 1, k0 + 32);

    bf16x8 ah[4], al_[4], bh[4], bl_[4];
#pragma unroll
    for (int m = 0; m < 4; ++m) {
      int ar = wr * 64 + m * 16 + fr;
      int pa = (ch ^ (ar & 7)) * 8;               // swizzled chunk (shorts)
      ah[m]  = *(const bf16x8*)&As[cur][ar * 64 + pa];
      al_[m] = *(const bf16x8*)&As[cur][ar * 64 + (pa ^ 32)];  // l-half: chunk^4
      int bc = wc * 64 + m * 16 + fr;
      int pb = (ch ^ (bc & 7)) * 8;
      bh[m]  = *(const bf16x8*)&Bs[cur][bc * 64 + pb];
      bl_[m] = *(const bf16x8*)&Bs[cur][bc * 64 + (pb ^ 32)];
    }
#pragma unroll
    for (int m = 0; m < 4; ++m)
#pragma unroll
      for (int n = 0; n < 4; ++n) {
        acc[m][n] = __builtin_amdgcn_mfma_f32_16x16x32_bf16(ah[m],  bh[n],  acc[m][n], 0, 0, 0);
        acc[m][n] = __builtin_amdgcn_mfma_f32_16x16x32_bf16(ah[m],  bl_[n], acc[m][n], 0, 0, 0);
        acc[m][n] = __builtin_amdgcn_mfma_f32_16x16x32_bf16(al_[m], bh[n],  acc[m][n], 0, 0, 0);
      }
    // one barrier per step: built-in vmcnt(0)+lgkmcnt(0) drain lands AFTER
    // the MFMA phase, so prefetch latency is hidden under compute.
    __syncthreads();
    cur ^= 1;
  }

  // ---- fused alpha: s1[row] = sum_c h[row][c]*a_src[hd][c], s2 likewise ----
  const float* as_v = av_s + hd * HIDC;
  const float* ad_v = av_d + hd * HIDC;
#pragma unroll
  for (int m = 0; m < 4; ++m)
#pragma unroll
    for (int i = 0; i < 4; ++i) {
      float s1 = 0.f, s2 = 0.f;
#pragma unroll
      for (int n = 0; n < 4; ++n) {
        int c = wc * 64 + n * 16 + (l & 15);
        float v = acc[m][n][i];
        s1 += v * as_v[c];
        s2 += v * ad_v[c];
      }
#pragma unroll
      for (int off = 1; off < 16; off <<= 1) {
        s1 += __shfl_xor(s1, off);
        s2 += __shfl_xor(s2, off);
      }
      if ((l & 15) == 0) {
        int rl = wr * 64 + m * 16 + (l >> 4) * 4 + i;
        red1[rl][wc] = s1;
        red2[rl][wc] = s2;
      }
    }
  __syncthreads();
  if (tid < 128) {
    int row = row0 + tid;
    if (row < M) {
      asrcO[row * H + hd] = red1[tid][0] + red1[tid][1];
      adstO[row * H + hd] = red2[tid][0] + red2[tid][1];
    }
  }

  // ---- C write ----
#pragma unroll
  for (int m = 0; m < 4; ++m) {
#pragma unroll
    for (int i = 0; i < 4; ++i) {
      int row = row0 + wr * 64 + m * 16 + (l >> 4) * 4 + i;
      if (row < M) {
#pragma unroll
        for (int n = 0; n < 4; ++n) {
          int colg = col0 + wc * 64 + n * 16 + (l & 15);
          if (Ch) Ch[(size_t)row * N + colg] = __float2half(acc[m][n][i]);
          else    Cf[(size_t)row * N + colg] = acc[m][n][i];
        }
      }
    }
  }
}

// ================== GAT aggregation, fp16 gather (layers 1/2) ==================
// Phase A (lanes over edges): e -> wave-max -> p=exp(e-m) cached in LDS + sum.
// Phase B (lanes over channels): 4-deep pipelined edge loop — 4 independent
// 256B gathers in flight per wave before the dependent FMAs (MLP fix).
__global__ __launch_bounds__(256) void k_aggregate16(
    const __half* __restrict__ h16,   // [N][512]
    const float* __restrict__ asrc, const float* __restrict__ adst,
    const int* __restrict__ row_ptr, const int* __restrict__ col,
    const float* __restrict__ bias,   // [512]
    short* __restrict__ oh, short* __restrict__ ol) {
  __shared__ float p_lds[NHEADS][DEGCAP];
  __shared__ int   s_lds[DEGCAP];

  int n = blockIdx.x;
  int w = threadIdx.x >> 6;
  int l = threadIdx.x & 63;
  int r0 = row_ptr[n], r1 = row_ptr[n + 1];
  int D = r1 - r0;
  float adn = adst[n * NHEADS + w];

  // ---- phase A: per-head max, then p into LDS + sum ----
  float m = -INFINITY;
  for (int jj = l; jj < D; jj += 64) {
    int s = col[r0 + jj];
    if (w == 0 && jj < DEGCAP) s_lds[jj] = s;
    float e = asrc[s * NHEADS + w] + adn;
    e = e > 0.f ? e : NEG_SLOPE * e;
    m = fmaxf(m, e);
    if (jj < DEGCAP) p_lds[w][jj] = e;   // stash raw e; exp after max known
  }
#pragma unroll
  for (int off = 32; off; off >>= 1) m = fmaxf(m, __shfl_xor(m, off));

  float ssum = 0.f;
  for (int jj = l; jj < D; jj += 64) {
    float e;
    if (jj < DEGCAP) e = p_lds[w][jj];
    else {
      int s = col[r0 + jj];
      e = asrc[s * NHEADS + w] + adn;
      e = e > 0.f ? e : NEG_SLOPE * e;
    }
    float p = __expf(e - m);
    ssum += p;
    if (jj < DEGCAP) p_lds[w][jj] = p;
  }
#pragma unroll
  for (int off = 32; off; off >>= 1) ssum += __shfl_xor(ssum, off);
  __syncthreads();  // publish p_lds / s_lds

  // ---- phase B: channel-parallel, 4-deep pipelined accumulation ----
  float acc0 = 0.f, acc1 = 0.f;
  int Dc = D < DEGCAP ? D : DEGCAP;
  const __half2* hb = (const __half2*)h16;
  int base = w * 64 + l;               // half2 index of this lane's channel pair
  int jj = 0;
  for (; jj + 4 <= Dc; jj += 4) {
    float p0 = p_lds[w][jj],     p1 = p_lds[w][jj + 1];
    float p2 = p_lds[w][jj + 2], p3 = p_lds[w][jj + 3];
    int s0 = s_lds[jj],     s1 = s_lds[jj + 1];
    int s2 = s_lds[jj + 2], s3 = s_lds[jj + 3];
    __half2 h0 = hb[(size_t)s0 * 256 + base];   // 4 independent gathers
    __half2 h1 = hb[(size_t)s1 * 256 + base];
    __half2 h2 = hb[(size_t)s2 * 256 + base];
    __half2 h3 = hb[(size_t)s3 * 256 + base];
    float2 v0 = __half22float2(h0), v1 = __half22float2(h1);
    float2 v2 = __half22float2(h2), v3 = __half22float2(h3);
    acc0 += p0 * v0.x; acc1 += p0 * v0.y;
    acc0 += p1 * v1.x; acc1 += p1 * v1.y;
    acc0 += p2 * v2.x; acc1 += p2 * v2.y;
    acc0 += p3 * v3.x; acc1 += p3 * v3.y;
  }
  for (; jj < Dc; ++jj) {
    float p = p_lds[w][jj];
    int s = s_lds[jj];
    float2 hv = __half22float2(hb[(size_t)s * 256 + base]);
    acc0 += p * hv.x;
    acc1 += p * hv.y;
  }
  for (jj = Dc; jj < D; ++jj) {  // rare overflow path
    int s = col[r0 + jj];
    float e = asrc[s * NHEADS + w] + adn;
    e = e > 0.f ? e : NEG_SLOPE * e;
    float p = __expf(e - m);
    float2 hv = __half22float2(hb[(size_t)s * 256 + base]);
    acc0 += p * hv.x;
    acc1 += p * hv.y;
  }

  float inv = 1.f / (ssum + 1e-16f);
  int c0 = w * 128 + 2 * l;
  float o0 = acc0 * inv + bias[c0];
  float o1 = acc1 * inv + bias[c0 + 1];
  o0 = o0 > 0.f ? o0 : (__expf(o0) - 1.f);  // ELU
  o1 = o1 > 0.f ? o1 : (__expf(o1) - 1.f);

  size_t i0 = (size_t)n * 512 + c0;
  unsigned short h0 = bf16hi(o0);
  unsigned short h1 = bf16hi(o1);
  float f0 = __uint_as_float((unsigned)h0 << 16);
  float f1 = __uint_as_float((unsigned)h1 << 16);
  unsigned short l0 = bf16hi(o0 - f0);
  unsigned short l1 = bf16hi(o1 - f1);
  *(unsigned*)(oh + i0) = (unsigned)h0 | ((unsigned)h1 << 16);
  *(unsigned*)(ol + i0) = (unsigned)l0 | ((unsigned)l1 << 16);
}

// ============== GAT aggregation, fp32 (layer 3, final output) ==============
// Phase-split + 4-deep pipeline (ported from k_aggregate16), 1 head.
__global__ __launch_bounds__(64) void k_aggregate(
    const float* __restrict__ h,      // [N][128]
    const float* __restrict__ asrc,
    const float* __restrict__ adst,
    const int* __restrict__ row_ptr,
    const int* __restrict__ col,
    const float* __restrict__ bias,
    float* __restrict__ outf) {
  __shared__ float p_lds[DEGCAP];
  __shared__ int   s_lds[DEGCAP];

  const int C = HIDC;
  int n = blockIdx.x;
  int l = threadIdx.x & 63;
  int r0 = row_ptr[n], r1 = row_ptr[n + 1];
  int D = r1 - r0;
  float adn = adst[n];

  // ---- phase A ----
  float m = -INFINITY;
  for (int jj = l; jj < D; jj += 64) {
    int s = col[r0 + jj];
    if (jj < DEGCAP) s_lds[jj] = s;
    float e = asrc[s] + adn;
    e = e > 0.f ? e : NEG_SLOPE * e;
    m = fmaxf(m, e);
    if (jj < DEGCAP) p_lds[jj] = e;
  }
#pragma unroll
  for (int off = 32; off; off >>= 1) m = fmaxf(m, __shfl_xor(m, off));

  float ssum = 0.f;
  for (int jj = l; jj < D; jj += 64) {
    float e;
    if (jj < DEGCAP) e = p_lds[jj];
    else {
      int s = col[r0 + jj];
      e = asrc[s] + adn;
      e = e > 0.f ? e : NEG_SLOPE * e;
    }
    float p = __expf(e - m);
    ssum += p;
    if (jj < DEGCAP) p_lds[jj] = p;
  }
#pragma unroll
  for (int off = 32; off; off >>= 1) ssum += __shfl_xor(ssum, off);
  __syncthreads();

  // ---- phase B: 4-deep pipelined ----
  float acc0 = 0.f, acc1 = 0.f;
  int Dc = D < DEGCAP ? D : DEGCAP;
  int jj = 0;
  for (; jj + 4 <= Dc; jj += 4) {
    float p0 = p_lds[jj], p1 = p_lds[jj + 1], p2 = p_lds[jj + 2], p3 = p_lds[jj + 3];
    const float* r0p = h + (size_t)s_lds[jj]     * C;
    const float* r1p = h + (size_t)s_lds[jj + 1] * C;
    const float* r2p = h + (size_t)s_lds[jj + 2] * C;
    const float* r3p = h + (size_t)s_lds[jj + 3] * C;
    float a0 = r0p[l], b0 = r0p[l + 64];
    float a1 = r1p[l], b1 = r1p[l + 64];
    float a2 = r2p[l], b2 = r2p[l + 64];
    float a3 = r3p[l], b3 = r3p[l + 64];
    acc0 += p0 * a0; acc1 += p0 * b0;
    acc0 += p1 * a1; acc1 += p1 * b1;
    acc0 += p2 * a2; acc1 += p2 * b2;
    acc0 += p3 * a3; acc1 += p3 * b3;
  }
  for (; jj < Dc; ++jj) {
    float p = p_lds[jj];
    const float* hr = h + (size_t)s_lds[jj] * C;
    acc0 += p * hr[l];
    acc1 += p * hr[l + 64];
  }
  for (jj = Dc; jj < D; ++jj) {
    int s = col[r0 + jj];
    float e = asrc[s] + adn;
    e = e > 0.f ? e : NEG_SLOPE * e;
    float p = __expf(e - m);
    const float* hr = h + (size_t)s * C;
    acc0 += p * hr[l];
    acc1 += p * hr[l + 64];
  }

  float inv = 1.f / (ssum + 1e-16f);
  outf[(size_t)n * C + l]      = acc0 * inv + bias[l];
  outf[(size_t)n * C + l + 64] = acc1 * inv + bias[l + 64];
}

// ============================ launcher ============================

extern "C" void kernel_launch(void* const* d_in, const int* in_sizes, int n_in,
                              void* d_out, int out_size, void* d_ws, size_t ws_size,
                              hipStream_t stream) {
  const float* x      = (const float*)d_in[0];
  const int*   ei     = (const int*)d_in[1];
  const float* W1     = (const float*)d_in[2];
  const float* a1_src = (const float*)d_in[3];
  const float* a1_dst = (const float*)d_in[4];
  const float* b1     = (const float*)d_in[5];
  const float* W2     = (const float*)d_in[6];
  const float* a2_src = (const float*)d_in[7];
  const float* a2_dst = (const float*)d_in[8];
  const float* b2     = (const float*)d_in[9];
  const float* W3     = (const float*)d_in[10];
  const float* a3_src = (const float*)d_in[11];
  const float* a3_dst = (const float*)d_in[12];
  const float* b3     = (const float*)d_in[13];
  float* out = (float*)d_out;

  char* ws = (char*)d_ws;
  size_t off = 0;
  auto alloc = [&](size_t bytes) {
    size_t r = off;
    off = (off + bytes + 255) & ~(size_t)255;
    return r;
  };
  short* Aih = (short*)(ws + alloc((size_t)MPAD * INC * 2));
  short* Ail = (short*)(ws + alloc((size_t)MPAD * INC * 2));
  short* w1h = (short*)(ws + alloc((size_t)512 * INC * 2));
  short* w1l = (short*)(ws + alloc((size_t)512 * INC * 2));
  short* w2h = (short*)(ws + alloc((size_t)512 * 512 * 2));
  short* w2l = (short*)(ws + alloc((size_t)512 * 512 * 2));
  short* w3h = (short*)(ws + alloc((size_t)128 * 512 * 2));
  short* w3l = (short*)(ws + alloc((size_t)128 * 512 * 2));
  __half* h16    = (__half*)(ws + alloc((size_t)MPAD * 512 * 2));
  float* hA      = (float*)(ws + alloc((size_t)NNODES * HIDC * 4));
  float* asrc    = (float*)(ws + alloc((size_t)NNODES * NHEADS * 4));
  float* adst    = (float*)(ws + alloc((size_t)NNODES * NHEADS * 4));
  int*   row_ptr = (int*)(ws + alloc((size_t)(NNODES + 1) * 4));
  int*   fill    = (int*)(ws + alloc((size_t)NNODES * 4));
  int*   cnt     = (int*)(ws + alloc((size_t)NNODES * 4));
  int*   colv    = (int*)(ws + alloc((size_t)(NEDGES + NNODES) * 4));

  const int TOT = NEDGES + NNODES;

  // ---- CSR build ----
  k_zero<<<(NNODES + 255) / 256, 256, 0, stream>>>(cnt, NNODES);
  k_count<<<(TOT + 255) / 256, 256, 0, stream>>>(ei, cnt);
  k_scan<<<1, 1024, 0, stream>>>(cnt, row_ptr, fill);
  k_fill<<<(TOT + 255) / 256, 256, 0, stream>>>(ei, fill, colv);

  // ---- decompose inputs & weights ----
  k_decomp<<<(NNODES * INC + 255) / 256, 256, 0, stream>>>(x, Aih, Ail, NNODES * INC);
  k_decomp_wt<<<dim3(512 / 32, INC / 32), 256, 0, stream>>>(W1, w1h, w1l, INC, 512);
  k_decomp_wt<<<dim3(512 / 32, 512 / 32), 256, 0, stream>>>(W2, w2h, w2l, 512, 512);
  k_decomp_wt<<<dim3(128 / 32, 512 / 32), 256, 0, stream>>>(W3, w3h, w3l, 512, 128);

  const int GY = MPAD / 128;  // 157

  // ---- layer 1 ----
  k_gemm_bf16<<<dim3(512 / 128, GY), 256, 0, stream>>>(
      Aih, Ail, w1h, w1l, nullptr, h16, a1_src, a1_dst, asrc, adst,
      NNODES, 512, INC, NHEADS);
  k_aggregate16<<<NNODES, 256, 0, stream>>>(h16, asrc, adst, row_ptr, colv,
                                            b1, Aih, Ail);

  // ---- layer 2 ----
  k_gemm_bf16<<<dim3(512 / 128, GY), 256, 0, stream>>>(
      Aih, Ail, w2h, w2l, nullptr, h16, a2_src, a2_dst, asrc, adst,
      NNODES, 512, 512, NHEADS);
  k_aggregate16<<<NNODES, 256, 0, stream>>>(h16, asrc, adst, row_ptr, colv,
                                            b2, Aih, Ail);

  // ---- layer 3 ----
  k_gemm_bf16<<<dim3(1, GY), 256, 0, stream>>>(
      Aih, Ail, w3h, w3l, hA, nullptr, a3_src, a3_dst, asrc, adst,
      NNODES, 128, 512, 1);
  k_aggregate<<<NNODES, 64, 0, stream>>>(hA, asrc, adst, row_ptr, colv, b3, out);
}